// Round 1
// baseline (2502.475 us; speedup 1.0000x reference)
//
#include <hip/hip_runtime.h>
#include <math.h>

#define DEV __device__ __forceinline__

namespace {
constexpr int B_ = 32, H_ = 256, W_ = 256;
constexpr size_t NPIX = (size_t)B_ * H_ * W_;   // 2,097,152
constexpr int TST = 17;                          // padded table stride (words) -> conflict-free LDS gathers

// ws layout (bytes)
constexpr size_t OFF_IDXA = 0;
constexpr size_t OFF_IDXB = NPIX;
constexpr size_t OFF_W1R  = 2 * NPIX;                    // 2304 floats: w1 rearranged [t][i][o]
constexpr size_t OFF_T9   = OFF_W1R + 2304 * 4;          // 9*33*TST floats (code 32 = zero entry)
constexpr size_t OFF_AT   = OFF_T9 + 9 * 33 * TST * 4;   // A   : 32*TST
constexpr size_t OFF_BT   = OFF_AT + 32 * TST * 4;       // Bc  : 32*TST   (contiguous after A)
constexpr size_t OFF_CBL  = OFF_BT + 32 * TST * 4;       // cb padded : 32*TST (contiguous after Bc)
constexpr size_t OFF_CBN  = OFF_CBL + 32 * TST * 4;      // 32 floats
constexpr size_t OFF_DEC  = OFF_CBN + 32 * 4;            // 32 floats
constexpr size_t OFF_LOSS = (OFF_DEC + 32 * 4 + 7) & ~(size_t)7;  // 5 doubles
constexpr size_t OFF_MASK = OFF_LOSS + 5 * 8;                     // 5 uint32
}

DEV float sigmoid_(float v) { return 1.0f / (1.0f + expf(-v)); }

// ---------------- setup: build tables, zero accumulators ----------------
__global__ void k_setup(const float* __restrict__ w1, const float* __restrict__ cb,
                        const float* __restrict__ tauw, const float* __restrict__ taub,
                        const float* __restrict__ decw, const float* __restrict__ decb,
                        float* __restrict__ w1r, float* __restrict__ T9,
                        float* __restrict__ At, float* __restrict__ Bt,
                        float* __restrict__ cbL, float* __restrict__ cbn,
                        float* __restrict__ dlut, double* __restrict__ lossS,
                        unsigned int* __restrict__ maskS)
{
    int tid = threadIdx.x;
    if (tid < 5) { lossS[tid] = 0.0; maskS[tid] = 0u; }
    for (int d = tid; d < 2304; d += 256) {             // w1r[t*256+i*16+o] = w1[o][i][t]
        int t = d >> 8, r = d & 255, i = r >> 4, o = r & 15;
        w1r[d] = w1[o * 144 + i * 9 + t];
    }
    for (int e = tid; e < 9 * 33; e += 256) {           // T9[(t*33+k)*TST + o]
        int t = e / 33, k = e % 33;
        float* dst = &T9[e * TST];
        for (int o = 0; o < 16; ++o) {
            float acc = 0.f;
            if (k < 32)
                for (int i = 0; i < 16; ++i)
                    acc = fmaf(w1[o * 144 + i * 9 + t], cb[k * 16 + i], acc);
            dst[o] = acc;
        }
    }
    if (tid < 32) {
        int k = tid;
        float nrm = 0.f;
        for (int c = 0; c < 16; ++c) { float v = cb[k * 16 + c]; nrm += v * v; }
        cbn[k] = nrm;
        float dacc = decb[0];
        for (int c = 0; c < 16; ++c) dacc = fmaf(decw[c], cb[k * 16 + c], dacc);
        dlut[k] = sigmoid_(dacc);
        for (int c = 0; c < 16; ++c) {
            float ta = taub[c];
            for (int i = 0; i < 16; ++i) ta = fmaf(tauw[c * 16 + i], cb[k * 16 + i], ta);
            float beta = sigmoid_(ta);
            At[k * TST + c]  = beta * cb[k * 16 + c];
            Bt[k * TST + c]  = 1.0f - beta;
            cbL[k * TST + c] = cb[k * 16 + c];
        }
    }
}

// ---------------- step 1: fused stem + up1/up2/tau/blend + VQ ----------------
__global__ __launch_bounds__(256) void k_iter1(
    const float* __restrict__ x, const float* __restrict__ stw, const float* __restrict__ stb,
    const float* __restrict__ w1r, const float* __restrict__ b1,
    const float* __restrict__ up2w, const float* __restrict__ b2,
    const float* __restrict__ tauw, const float* __restrict__ taub,
    const float* __restrict__ cb, const float* __restrict__ cbn,
    unsigned char* __restrict__ idx_out, double* __restrict__ lossS,
    unsigned int* __restrict__ maskS)
{
    __shared__ float xt[20 * 20];
    __shared__ float st[16][324];     // state0 tile, SoA [c][pix], 18x18
    __shared__ unsigned int bm;
    const int lx = threadIdx.x, ly = threadIdx.y;
    const int lid = ly * 16 + lx;
    const int b = blockIdx.z, oy = blockIdx.y * 16, ox = blockIdx.x * 16;
    if (lid == 0) bm = 0u;
    const float* xb = x + (size_t)b * (H_ * W_);
    for (int i = lid; i < 400; i += 256) {
        int iy = i / 20, ix = i % 20;
        int gy = oy - 2 + iy, gx = ox - 2 + ix;
        float v = 0.f;
        if (gy >= 0 && gy < H_ && gx >= 0 && gx < W_) v = xb[gy * W_ + gx];
        xt[i] = v;
    }
    __syncthreads();
    for (int p = lid; p < 324; p += 256) {   // stem conv -> state0 (zero outside image)
        int sy = p / 18, sx = p % 18;
        int gy = oy - 1 + sy, gx = ox - 1 + sx;
        bool inb = (gy >= 0 && gy < H_ && gx >= 0 && gx < W_);
        #pragma unroll
        for (int o = 0; o < 16; ++o) {
            float acc = stb[o];
            #pragma unroll
            for (int dy = 0; dy < 3; ++dy)
                #pragma unroll
                for (int dx = 0; dx < 3; ++dx)
                    acc = fmaf(stw[o * 9 + dy * 3 + dx], xt[(sy + dy) * 20 + sx + dx], acc);
            st[o][p] = inb ? fmaxf(acc, 0.f) : 0.f;
        }
    }
    __syncthreads();
    float u[16];
    #pragma unroll
    for (int o = 0; o < 16; ++o) u[o] = b1[o];
    #pragma unroll
    for (int t = 0; t < 9; ++t) {            // up1 3x3 conv
        int pn = (ly + t / 3) * 18 + lx + t % 3;
        #pragma unroll
        for (int i = 0; i < 16; ++i) {
            float s = st[i][pn];
            const float* wr = &w1r[t * 256 + i * 16];  // wave-uniform -> s_load
            #pragma unroll
            for (int o = 0; o < 16; ++o) u[o] = fmaf(wr[o], s, u[o]);
        }
    }
    const int p0 = (ly + 1) * 18 + lx + 1;
    float scv[16];
    #pragma unroll
    for (int c = 0; c < 16; ++c) scv[c] = st[c][p0];
    #pragma unroll
    for (int i = 0; i < 16; ++i) u[i] = fmaxf(u[i], 0.f);
    float z[16];
    #pragma unroll
    for (int o = 0; o < 16; ++o) {           // up2 1x1
        float acc = b2[o];
        #pragma unroll
        for (int i = 0; i < 16; ++i) acc = fmaf(up2w[o * 16 + i], u[i], acc);
        z[o] = acc;
    }
    #pragma unroll
    for (int c = 0; c < 16; ++c) {           // tau + blend
        float ta = taub[c];
        #pragma unroll
        for (int i = 0; i < 16; ++i) ta = fmaf(tauw[c * 16 + i], scv[i], ta);
        float beta = sigmoid_(ta);
        z[c] = beta * scv[c] + (1.0f - beta) * z[c];
    }
    // VQ: argmin_k (z^2 + |cb_k|^2) - 2 z.cb_k, first-min tie-break
    float z2 = 0.f;
    #pragma unroll
    for (int c = 0; c < 16; ++c) z2 += z[c] * z[c];
    float best = 3.4e38f; int bk = 0;
    for (int k = 0; k < 32; ++k) {
        float dot = 0.f;
        #pragma unroll
        for (int c = 0; c < 16; ++c) dot = fmaf(cb[k * 16 + c], z[c], dot);
        float d = (z2 + cbn[k]) - 2.0f * dot;
        if (d < best) { best = d; bk = k; }
    }
    idx_out[(size_t)b * (H_ * W_) + (size_t)(oy + ly) * W_ + (ox + lx)] = (unsigned char)bk;
    float lp = 0.f;
    #pragma unroll
    for (int c = 0; c < 16; ++c) { float df = cb[bk * 16 + c] - z[c]; lp = fmaf(df, df, lp); }
    for (int off = 32; off > 0; off >>= 1) lp += __shfl_down(lp, off, 64);
    if ((lid & 63) == 0) atomicAdd(lossS, (double)lp);
    atomicOr(&bm, 1u << bk);
    __syncthreads();
    if (lid == 0) atomicOr(maskS, bm);
}

// ---------------- steps 2..5: quantized state, table-driven ----------------
__global__ __launch_bounds__(256) void k_qstep(
    const unsigned char* __restrict__ idx_in, unsigned char* __restrict__ idx_out,
    const float* __restrict__ T9, const float* __restrict__ ABL,  // A|Bc|cbL contiguous
    const float* __restrict__ cbn, const float* __restrict__ cb,
    const float* __restrict__ up2w, const float* __restrict__ b1, const float* __restrict__ b2,
    double* __restrict__ lossS, unsigned int* __restrict__ maskS)
{
    __shared__ float T9s[9 * 33 * TST];
    __shared__ float ABs[3 * 32 * TST];
    __shared__ unsigned char ct[324];
    __shared__ unsigned int bm;
    const int lx = threadIdx.x, ly = threadIdx.y;
    const int lid = ly * 16 + lx;
    const int b = blockIdx.z, oy = blockIdx.y * 16, ox = blockIdx.x * 16;
    if (lid == 0) bm = 0u;
    for (int i = lid; i < 9 * 33 * TST; i += 256) T9s[i] = T9[i];
    for (int i = lid; i < 3 * 32 * TST; i += 256) ABs[i] = ABL[i];
    const unsigned char* ib = idx_in + (size_t)b * (H_ * W_);
    for (int i = lid; i < 324; i += 256) {
        int iy = i / 18, ix = i % 18;
        int gy = oy - 1 + iy, gx = ox - 1 + ix;
        unsigned char v = 32;                 // sentinel -> zero vector (conv zero-pad)
        if (gy >= 0 && gy < H_ && gx >= 0 && gx < W_) v = ib[gy * W_ + gx];
        ct[i] = v;
    }
    __syncthreads();
    float u[16];
    #pragma unroll
    for (int o = 0; o < 16; ++o) u[o] = b1[o];
    #pragma unroll
    for (int t = 0; t < 9; ++t) {             // up1 conv = 9 table adds
        int code = ct[(ly + t / 3) * 18 + lx + t % 3];
        const float* e = &T9s[(t * 33 + code) * TST];
        #pragma unroll
        for (int o = 0; o < 16; ++o) u[o] += e[o];
    }
    #pragma unroll
    for (int i = 0; i < 16; ++i) u[i] = fmaxf(u[i], 0.f);
    float z[16];
    #pragma unroll
    for (int o = 0; o < 16; ++o) {            // up2 1x1
        float acc = b2[o];
        #pragma unroll
        for (int i = 0; i < 16; ++i) acc = fmaf(up2w[o * 16 + i], u[i], acc);
        z[o] = acc;
    }
    const int kc = ct[(ly + 1) * 18 + lx + 1];
    #pragma unroll
    for (int c = 0; c < 16; ++c)              // blend via per-code tables
        z[c] = fmaf(ABs[32 * TST + kc * TST + c], z[c], ABs[kc * TST + c]);
    // VQ
    float z2 = 0.f;
    #pragma unroll
    for (int c = 0; c < 16; ++c) z2 += z[c] * z[c];
    float best = 3.4e38f; int bk = 0;
    for (int k = 0; k < 32; ++k) {
        float dot = 0.f;
        #pragma unroll
        for (int c = 0; c < 16; ++c) dot = fmaf(cb[k * 16 + c], z[c], dot);
        float d = (z2 + cbn[k]) - 2.0f * dot;
        if (d < best) { best = d; bk = k; }
    }
    idx_out[(size_t)b * (H_ * W_) + (size_t)(oy + ly) * W_ + (ox + lx)] = (unsigned char)bk;
    const float* cbl = &ABs[64 * TST + bk * TST];
    float lp = 0.f;
    #pragma unroll
    for (int c = 0; c < 16; ++c) { float df = cbl[c] - z[c]; lp = fmaf(df, df, lp); }
    for (int off = 32; off > 0; off >>= 1) lp += __shfl_down(lp, off, 64);
    if ((lid & 63) == 0) atomicAdd(lossS, (double)lp);
    atomicOr(&bm, 1u << bk);
    __syncthreads();
    if (lid == 0) atomicOr(maskS, bm);
}

// ---------------- final: decode LUT + scalar outputs ----------------
__global__ __launch_bounds__(256) void k_final(
    const unsigned char* __restrict__ idxF, const float* __restrict__ dlut,
    float* __restrict__ out, const double* __restrict__ lossS,
    const unsigned int* __restrict__ maskS)
{
    __shared__ float lut[32];
    if (threadIdx.x < 32) lut[threadIdx.x] = dlut[threadIdx.x];
    __syncthreads();
    size_t i = (size_t)blockIdx.x * 256 + threadIdx.x;
    uchar4 c4 = ((const uchar4*)idxF)[i];
    float4 o4 = make_float4(lut[c4.x], lut[c4.y], lut[c4.z], lut[c4.w]);
    ((float4*)out)[i] = o4;
    if (blockIdx.x == 0 && threadIdx.x == 0) {
        double vq = 0.0; float us = 0.f;
        for (int s = 0; s < 5; ++s) {
            vq += 1.25 * lossS[s] / 33554432.0;     // (codebook + 0.25*commit) loss, mean over B*C*H*W
            us += (float)__popc(maskS[s]) / 32.0f;
        }
        out[NPIX]     = (float)(vq / 5.0);
        out[NPIX + 1] = us / 5.0f;
    }
}

extern "C" void kernel_launch(void* const* d_in, const int* in_sizes, int n_in,
                              void* d_out, int out_size, void* d_ws, size_t ws_size,
                              hipStream_t stream)
{
    const float* x   = (const float*)d_in[0];
    const float* stw = (const float*)d_in[1];
    const float* stb = (const float*)d_in[2];
    const float* w1  = (const float*)d_in[3];
    const float* b1  = (const float*)d_in[4];
    const float* u2w = (const float*)d_in[5];
    const float* b2  = (const float*)d_in[6];
    const float* tw  = (const float*)d_in[7];
    const float* tb  = (const float*)d_in[8];
    const float* cb  = (const float*)d_in[9];
    const float* dw  = (const float*)d_in[10];
    const float* db  = (const float*)d_in[11];
    // n_steps (d_in[12]) is fixed at 5 by setup_inputs.

    char* ws = (char*)d_ws;
    unsigned char* idxA = (unsigned char*)(ws + OFF_IDXA);
    unsigned char* idxB = (unsigned char*)(ws + OFF_IDXB);
    float* w1r  = (float*)(ws + OFF_W1R);
    float* T9   = (float*)(ws + OFF_T9);
    float* At   = (float*)(ws + OFF_AT);
    float* Bt   = (float*)(ws + OFF_BT);
    float* cbL  = (float*)(ws + OFF_CBL);
    float* cbn  = (float*)(ws + OFF_CBN);
    float* dlut = (float*)(ws + OFF_DEC);
    double* lossS = (double*)(ws + OFF_LOSS);
    unsigned int* maskS = (unsigned int*)(ws + OFF_MASK);

    dim3 blk(16, 16, 1);
    dim3 grd(W_ / 16, H_ / 16, B_);
    k_setup<<<1, 256, 0, stream>>>(w1, cb, tw, tb, dw, db, w1r, T9, At, Bt, cbL, cbn, dlut, lossS, maskS);
    k_iter1<<<grd, blk, 0, stream>>>(x, stw, stb, w1r, b1, u2w, b2, tw, tb, cb, cbn,
                                     idxA, lossS + 0, maskS + 0);
    k_qstep<<<grd, blk, 0, stream>>>(idxA, idxB, T9, At, cbn, cb, u2w, b1, b2, lossS + 1, maskS + 1);
    k_qstep<<<grd, blk, 0, stream>>>(idxB, idxA, T9, At, cbn, cb, u2w, b1, b2, lossS + 2, maskS + 2);
    k_qstep<<<grd, blk, 0, stream>>>(idxA, idxB, T9, At, cbn, cb, u2w, b1, b2, lossS + 3, maskS + 3);
    k_qstep<<<grd, blk, 0, stream>>>(idxB, idxA, T9, At, cbn, cb, u2w, b1, b2, lossS + 4, maskS + 4);
    k_final<<<dim3((unsigned)(NPIX / 4 / 256)), 256, 0, stream>>>(idxA, dlut, (float*)d_out, lossS, maskS);
}

// Round 2
// 1672.143 us; speedup vs baseline: 1.4966x; 1.4966x over previous
//
#include <hip/hip_runtime.h>
#include <math.h>

#define DEV __device__ __forceinline__

namespace {
constexpr int B_ = 32, H_ = 256, W_ = 256;
constexpr size_t NPIX = (size_t)B_ * H_ * W_;   // 2,097,152

// ---- qstep table block (float offsets), entries stride 20 (80B, b128-aligned, bank-spread) ----
constexpr int QT9 = 0;            // [9][33] entries: T9[t][code][o] (+b1 baked into t==4)
constexpr int QCB = 5940;         // 32 entries: cb[c], slot16 = |cb|^2
constexpr int QA2 = 6580;         // 32 entries: beta*cb + (1-beta)*b2
constexpr int QBC = 7220;         // 32 entries: 1-beta
constexpr int QU2 = 7860;         // 16 entries: up2w transposed [i][o]
constexpr int QTOT = 8180;        // floats (32,720 B), /4 = 2045 exact

// ---- iter1 table block ----
constexpr int IW1 = 0;            // [9][16] entries: w1[t][i][o]
constexpr int IU2 = 2880;         // 16 entries: up2w^T [i][o]
constexpr int ITA = 3200;         // 16 entries: tauw^T [i][c]
constexpr int ICB = 3520;         // 32 entries: cb + |cb|^2
constexpr int IB1 = 4160;         // 16 floats
constexpr int IB2 = 4176;         // 16
constexpr int ITB = 4192;         // 16 (tau bias)
constexpr int ISW = 4208;         // stem weights [9][20]: sw[t][o]
constexpr int ISB = 4388;         // stem bias 16
constexpr int ITOT = 4404;        // floats (17,616 B), /4 = 1101 exact

// ws byte offsets
constexpr size_t OFF_QTAB = 2 * NPIX;                       // 16B aligned
constexpr size_t OFF_ITAB = OFF_QTAB + (size_t)QTOT * 4;    // +32720 (16B aligned)
constexpr size_t OFF_DLUT = OFF_ITAB + (size_t)ITOT * 4;    // +17616
constexpr size_t OFF_LOSS = (OFF_DLUT + 128 + 7) & ~(size_t)7;
constexpr size_t OFF_MASK = OFF_LOSS + 5 * 8;
}

DEV float4 f4z() { return make_float4(0.f, 0.f, 0.f, 0.f); }
DEV float4 f4ma(float4 a, float4 w, float s) {
    a.x = fmaf(w.x, s, a.x); a.y = fmaf(w.y, s, a.y);
    a.z = fmaf(w.z, s, a.z); a.w = fmaf(w.w, s, a.w); return a;
}
DEV float4 f4add(float4 a, float4 b) { a.x += b.x; a.y += b.y; a.z += b.z; a.w += b.w; return a; }
DEV float4 f4relu(float4 a) {
    a.x = fmaxf(a.x, 0.f); a.y = fmaxf(a.y, 0.f);
    a.z = fmaxf(a.z, 0.f); a.w = fmaxf(a.w, 0.f); return a;
}
DEV float4 f4fmav(float4 a, float4 b, float4 c) {   // a + b*c componentwise
    a.x = fmaf(b.x, c.x, a.x); a.y = fmaf(b.y, c.y, a.y);
    a.z = fmaf(b.z, c.z, a.z); a.w = fmaf(b.w, c.w, a.w); return a;
}
DEV float4 f4sig(float4 t) {
    t.x = 1.f / (1.f + expf(-t.x)); t.y = 1.f / (1.f + expf(-t.y));
    t.z = 1.f / (1.f + expf(-t.z)); t.w = 1.f / (1.f + expf(-t.w)); return t;
}
// ascending-c scalar fma chain (matches round-1 numerics shape)
DEV float dot16(float4 a0, float4 a1, float4 a2, float4 a3,
                float4 b0, float4 b1, float4 b2, float4 b3) {
    float d = 0.f;
    d = fmaf(a0.x, b0.x, d); d = fmaf(a0.y, b0.y, d); d = fmaf(a0.z, b0.z, d); d = fmaf(a0.w, b0.w, d);
    d = fmaf(a1.x, b1.x, d); d = fmaf(a1.y, b1.y, d); d = fmaf(a1.z, b1.z, d); d = fmaf(a1.w, b1.w, d);
    d = fmaf(a2.x, b2.x, d); d = fmaf(a2.y, b2.y, d); d = fmaf(a2.z, b2.z, d); d = fmaf(a2.w, b2.w, d);
    d = fmaf(a3.x, b3.x, d); d = fmaf(a3.y, b3.y, d); d = fmaf(a3.z, b3.z, d); d = fmaf(a3.w, b3.w, d);
    return d;
}
DEV float sq16(float4 a0, float4 a1, float4 a2, float4 a3,
               float4 b0, float4 b1, float4 b2, float4 b3) {  // sum (a-b)^2
    float d = 0.f, t;
    t = a0.x - b0.x; d = fmaf(t, t, d); t = a0.y - b0.y; d = fmaf(t, t, d);
    t = a0.z - b0.z; d = fmaf(t, t, d); t = a0.w - b0.w; d = fmaf(t, t, d);
    t = a1.x - b1.x; d = fmaf(t, t, d); t = a1.y - b1.y; d = fmaf(t, t, d);
    t = a1.z - b1.z; d = fmaf(t, t, d); t = a1.w - b1.w; d = fmaf(t, t, d);
    t = a2.x - b2.x; d = fmaf(t, t, d); t = a2.y - b2.y; d = fmaf(t, t, d);
    t = a2.z - b2.z; d = fmaf(t, t, d); t = a2.w - b2.w; d = fmaf(t, t, d);
    t = a3.x - b3.x; d = fmaf(t, t, d); t = a3.y - b3.y; d = fmaf(t, t, d);
    t = a3.z - b3.z; d = fmaf(t, t, d); t = a3.w - b3.w; d = fmaf(t, t, d);
    return d;
}

// ---------------- setup: build all tables in ws, zero accumulators ----------------
__global__ void k_setup(const float* __restrict__ w1, const float* __restrict__ b1,
                        const float* __restrict__ u2w, const float* __restrict__ b2,
                        const float* __restrict__ tw, const float* __restrict__ tb,
                        const float* __restrict__ cb, const float* __restrict__ stw,
                        const float* __restrict__ stb, const float* __restrict__ dw,
                        const float* __restrict__ db,
                        float* __restrict__ gQ, float* __restrict__ gI,
                        float* __restrict__ dlut, double* __restrict__ lossS,
                        unsigned int* __restrict__ maskS)
{
    int tid = threadIdx.x;
    if (tid < 5) { lossS[tid] = 0.0; maskS[tid] = 0u; }
    for (int e = tid; e < 297; e += 256) {          // T9 entries
        int t = e / 33, k = e % 33;
        float* dst = &gQ[QT9 + e * 20];
        for (int o = 0; o < 16; ++o) {
            float acc = 0.f;
            if (k < 32) {
                for (int i = 0; i < 16; ++i)
                    acc = fmaf(w1[o * 144 + i * 9 + t], cb[k * 16 + i], acc);
                if (t == 4) acc += b1[o];           // bias baked into center tap
            }
            dst[o] = acc;
        }
        dst[16] = dst[17] = dst[18] = dst[19] = 0.f;
    }
    if (tid < 32) {
        int k = tid;
        float nrm = 0.f;
        for (int c = 0; c < 16; ++c) { float v = cb[k * 16 + c]; nrm = fmaf(v, v, nrm); }
        for (int c = 0; c < 16; ++c) { gQ[QCB + k * 20 + c] = cb[k * 16 + c]; gI[ICB + k * 20 + c] = cb[k * 16 + c]; }
        gQ[QCB + k * 20 + 16] = nrm; gI[ICB + k * 20 + 16] = nrm;
        for (int c = 17; c < 20; ++c) { gQ[QCB + k * 20 + c] = 0.f; gI[ICB + k * 20 + c] = 0.f; }
        float dacc = db[0];
        for (int c = 0; c < 16; ++c) dacc = fmaf(dw[c], cb[k * 16 + c], dacc);
        dlut[k] = 1.f / (1.f + expf(-dacc));
        for (int c = 0; c < 16; ++c) {
            float ta = tb[c];
            for (int i = 0; i < 16; ++i) ta = fmaf(tw[c * 16 + i], cb[k * 16 + i], ta);
            float beta = 1.f / (1.f + expf(-ta));
            gQ[QA2 + k * 20 + c] = beta * cb[k * 16 + c] + (1.f - beta) * b2[c];
            gQ[QBC + k * 20 + c] = 1.f - beta;
        }
        for (int c = 16; c < 20; ++c) { gQ[QA2 + k * 20 + c] = 0.f; gQ[QBC + k * 20 + c] = 0.f; }
    }
    if (tid < 16) {
        int i = tid;
        for (int o = 0; o < 16; ++o) { gQ[QU2 + i * 20 + o] = u2w[o * 16 + i]; gI[IU2 + i * 20 + o] = u2w[o * 16 + i]; }
        for (int o = 16; o < 20; ++o) { gQ[QU2 + i * 20 + o] = 0.f; gI[IU2 + i * 20 + o] = 0.f; }
        for (int c = 0; c < 16; ++c) gI[ITA + i * 20 + c] = tw[c * 16 + i];
        for (int c = 16; c < 20; ++c) gI[ITA + i * 20 + c] = 0.f;
        gI[IB1 + i] = b1[i]; gI[IB2 + i] = b2[i]; gI[ITB + i] = tb[i]; gI[ISB + i] = stb[i];
    }
    for (int e = tid; e < 144; e += 256) {          // w1 rearranged [t][i][o]
        int t = e / 16, i = e % 16;
        float* dst = &gI[IW1 + e * 20];
        for (int o = 0; o < 16; ++o) dst[o] = w1[o * 144 + i * 9 + t];
        dst[16] = dst[17] = dst[18] = dst[19] = 0.f;
    }
    if (tid < 9) {
        int t = tid;
        for (int o = 0; o < 16; ++o) gI[ISW + t * 20 + o] = stw[o * 9 + t];
        for (int o = 16; o < 20; ++o) gI[ISW + t * 20 + o] = 0.f;
    }
}

// ---------------- step 1: fused stem + up1/up2/tau/blend + VQ (pure-DS hot loop) ----------------
__global__ __launch_bounds__(256, 3) void k_iter1(
    const float* __restrict__ x, const float* __restrict__ gI,
    unsigned char* __restrict__ idx_out, double* __restrict__ lossS,
    unsigned int* __restrict__ maskS)
{
    __shared__ float xt[400];           // 20x20 input tile
    __shared__ float st[324 * 20];      // state0 AoS [pix18x18][20]
    __shared__ float tab[ITOT];         // all weights
    __shared__ unsigned int bm;
    const int lx = threadIdx.x, ly = threadIdx.y;
    const int lid = ly * 16 + lx;
    const int b = blockIdx.z, oy = blockIdx.y * 16, ox = blockIdx.x * 16;
    if (lid == 0) bm = 0u;
    for (int i = lid; i < ITOT / 4; i += 256) ((float4*)tab)[i] = ((const float4*)gI)[i];
    const float* xb = x + (size_t)b * (H_ * W_);
    for (int i = lid; i < 400; i += 256) {
        int iy = i / 20, ix = i % 20;
        int gy = oy - 2 + iy, gx = ox - 2 + ix;
        float v = 0.f;
        if ((unsigned)gy < (unsigned)H_ && (unsigned)gx < (unsigned)W_) v = xb[gy * W_ + gx];
        xt[i] = v;
    }
    __syncthreads();
    for (int q = lid; q < 324; q += 256) {          // stem conv -> st (relu, zero outside)
        int sy = q / 18, sx = q % 18;
        int gy = oy - 1 + sy, gx = ox - 1 + sx;
        bool inb = ((unsigned)gy < (unsigned)H_ && (unsigned)gx < (unsigned)W_);
        float4 a0 = *(const float4*)&tab[ISB];
        float4 a1 = *(const float4*)&tab[ISB + 4];
        float4 a2 = *(const float4*)&tab[ISB + 8];
        float4 a3 = *(const float4*)&tab[ISB + 12];
        #pragma unroll
        for (int t = 0; t < 9; ++t) {
            float xv = xt[(sy + t / 3) * 20 + sx + t % 3];
            const float4* w4 = (const float4*)&tab[ISW + t * 20];
            a0 = f4ma(a0, w4[0], xv); a1 = f4ma(a1, w4[1], xv);
            a2 = f4ma(a2, w4[2], xv); a3 = f4ma(a3, w4[3], xv);
        }
        a0 = f4relu(a0); a1 = f4relu(a1); a2 = f4relu(a2); a3 = f4relu(a3);
        if (!inb) { a0 = f4z(); a1 = f4z(); a2 = f4z(); a3 = f4z(); }
        float4* d = (float4*)&st[q * 20];
        d[0] = a0; d[1] = a1; d[2] = a2; d[3] = a3;
    }
    __syncthreads();
    // ---- up1: 9 taps, state b128 reads + uniform weight b128 broadcasts ----
    float4 u0 = ((const float4*)&tab[IB1])[0], u1 = ((const float4*)&tab[IB1])[1],
           u2 = ((const float4*)&tab[IB1])[2], u3 = ((const float4*)&tab[IB1])[3];
#define UPD1(E, S) { const float4* w4 = (const float4*)&tab[IW1 + (E) * 20]; \
    u0 = f4ma(u0, w4[0], S); u1 = f4ma(u1, w4[1], S); u2 = f4ma(u2, w4[2], S); u3 = f4ma(u3, w4[3], S); }
    #pragma unroll
    for (int t = 0; t < 9; ++t) {
        const float4* sp = (const float4*)&st[((ly + t / 3) * 18 + lx + t % 3) * 20];
        float4 sA = sp[0], sB = sp[1], sC = sp[2], sD = sp[3];
        const int e = t * 16;
        UPD1(e + 0, sA.x) UPD1(e + 1, sA.y) UPD1(e + 2, sA.z) UPD1(e + 3, sA.w)
        UPD1(e + 4, sB.x) UPD1(e + 5, sB.y) UPD1(e + 6, sB.z) UPD1(e + 7, sB.w)
        UPD1(e + 8, sC.x) UPD1(e + 9, sC.y) UPD1(e + 10, sC.z) UPD1(e + 11, sC.w)
        UPD1(e + 12, sD.x) UPD1(e + 13, sD.y) UPD1(e + 14, sD.z) UPD1(e + 15, sD.w)
    }
#undef UPD1
    u0 = f4relu(u0); u1 = f4relu(u1); u2 = f4relu(u2); u3 = f4relu(u3);
    const float4* cp = (const float4*)&st[((ly + 1) * 18 + lx + 1) * 20];
    float4 c0 = cp[0], c1 = cp[1], c2 = cp[2], c3 = cp[3];    // center state
    // ---- up2 ----
    float4 v0 = ((const float4*)&tab[IB2])[0], v1 = ((const float4*)&tab[IB2])[1],
           v2 = ((const float4*)&tab[IB2])[2], v3 = ((const float4*)&tab[IB2])[3];
#define UPD2(I, S) { const float4* w4 = (const float4*)&tab[IU2 + (I) * 20]; \
    v0 = f4ma(v0, w4[0], S); v1 = f4ma(v1, w4[1], S); v2 = f4ma(v2, w4[2], S); v3 = f4ma(v3, w4[3], S); }
    UPD2(0, u0.x) UPD2(1, u0.y) UPD2(2, u0.z) UPD2(3, u0.w)
    UPD2(4, u1.x) UPD2(5, u1.y) UPD2(6, u1.z) UPD2(7, u1.w)
    UPD2(8, u2.x) UPD2(9, u2.y) UPD2(10, u2.z) UPD2(11, u2.w)
    UPD2(12, u3.x) UPD2(13, u3.y) UPD2(14, u3.z) UPD2(15, u3.w)
#undef UPD2
    // ---- tau ----
    float4 t0 = ((const float4*)&tab[ITB])[0], t1 = ((const float4*)&tab[ITB])[1],
           t2 = ((const float4*)&tab[ITB])[2], t3 = ((const float4*)&tab[ITB])[3];
#define UPDT(I, S) { const float4* w4 = (const float4*)&tab[ITA + (I) * 20]; \
    t0 = f4ma(t0, w4[0], S); t1 = f4ma(t1, w4[1], S); t2 = f4ma(t2, w4[2], S); t3 = f4ma(t3, w4[3], S); }
    UPDT(0, c0.x) UPDT(1, c0.y) UPDT(2, c0.z) UPDT(3, c0.w)
    UPDT(4, c1.x) UPDT(5, c1.y) UPDT(6, c1.z) UPDT(7, c1.w)
    UPDT(8, c2.x) UPDT(9, c2.y) UPDT(10, c2.z) UPDT(11, c2.w)
    UPDT(12, c3.x) UPDT(13, c3.y) UPDT(14, c3.z) UPDT(15, c3.w)
#undef UPDT
    // blend: z = v + beta*(c - v)
    float4 e0 = f4sig(t0), e1 = f4sig(t1), e2 = f4sig(t2), e3 = f4sig(t3);
    float4 z0, z1, z2, z3;
    z0.x = fmaf(e0.x, c0.x - v0.x, v0.x); z0.y = fmaf(e0.y, c0.y - v0.y, v0.y);
    z0.z = fmaf(e0.z, c0.z - v0.z, v0.z); z0.w = fmaf(e0.w, c0.w - v0.w, v0.w);
    z1.x = fmaf(e1.x, c1.x - v1.x, v1.x); z1.y = fmaf(e1.y, c1.y - v1.y, v1.y);
    z1.z = fmaf(e1.z, c1.z - v1.z, v1.z); z1.w = fmaf(e1.w, c1.w - v1.w, v1.w);
    z2.x = fmaf(e2.x, c2.x - v2.x, v2.x); z2.y = fmaf(e2.y, c2.y - v2.y, v2.y);
    z2.z = fmaf(e2.z, c2.z - v2.z, v2.z); z2.w = fmaf(e2.w, c2.w - v2.w, v2.w);
    z3.x = fmaf(e3.x, c3.x - v3.x, v3.x); z3.y = fmaf(e3.y, c3.y - v3.y, v3.y);
    z3.z = fmaf(e3.z, c3.z - v3.z, v3.z); z3.w = fmaf(e3.w, c3.w - v3.w, v3.w);
    // ---- VQ ----
    float zz = dot16(z0, z1, z2, z3, z0, z1, z2, z3);
    float best = 3.4e38f; int bk = 0;
    #pragma unroll 8
    for (int k = 0; k < 32; ++k) {
        const float4* q = (const float4*)&tab[ICB + k * 20];
        float4 q0 = q[0], q1 = q[1], q2 = q[2], q3 = q[3];
        float cn = tab[ICB + k * 20 + 16];
        float dot = dot16(q0, q1, q2, q3, z0, z1, z2, z3);
        float d = (zz + cn) - 2.0f * dot;
        if (d < best) { best = d; bk = k; }
    }
    idx_out[(size_t)b * (H_ * W_) + (size_t)(oy + ly) * W_ + (ox + lx)] = (unsigned char)bk;
    const float4* qb = (const float4*)&tab[ICB + bk * 20];
    float lp = sq16(qb[0], qb[1], qb[2], qb[3], z0, z1, z2, z3);
    for (int off = 32; off > 0; off >>= 1) lp += __shfl_down(lp, off, 64);
    if ((lid & 63) == 0) atomicAdd(lossS, (double)lp);
    atomicOr(&bm, 1u << bk);
    __syncthreads();
    if (lid == 0) atomicOr(maskS, bm);
}

// ---------------- steps 2..5: table-driven, 2 pixels/thread, pure-DS hot loop ----------------
__global__ __launch_bounds__(256, 4) void k_qstep(
    const unsigned char* __restrict__ idx_in, unsigned char* __restrict__ idx_out,
    const float* __restrict__ gQ, double* __restrict__ lossS,
    unsigned int* __restrict__ maskS)
{
    __shared__ float tab[QTOT];         // 32,720 B
    __shared__ unsigned char ct[18 * 40];
    __shared__ unsigned int bm;
    const int tx = threadIdx.x, ty = threadIdx.y;
    const int lid = ty * 16 + tx;
    const int b = blockIdx.z, oy = blockIdx.y * 16, ox = blockIdx.x * 32;
    if (lid == 0) bm = 0u;
    for (int i = lid; i < QTOT / 4; i += 256) ((float4*)tab)[i] = ((const float4*)gQ)[i];
    const unsigned char* ib = idx_in + (size_t)b * (H_ * W_);
    for (int i = lid; i < 18 * 34; i += 256) {
        int r = i / 34, c = i % 34;
        int gy = oy - 1 + r, gx = ox - 1 + c;
        unsigned char v = 32;           // sentinel -> zero vector
        if ((unsigned)gy < (unsigned)H_ && (unsigned)gx < (unsigned)W_) v = ib[gy * W_ + gx];
        ct[r * 40 + c] = v;
    }
    __syncthreads();
    const int cx = tx * 2;
    float4 u00 = f4z(), u01 = f4z(), u02 = f4z(), u03 = f4z();
    float4 u10 = f4z(), u11 = f4z(), u12 = f4z(), u13 = f4z();
    #pragma unroll
    for (int t = 0; t < 9; ++t) {       // up1 conv = table adds (b1 baked into t==4)
        int row = (ty + t / 3) * 40 + cx + t % 3;
        int k0 = ct[row], k1 = ct[row + 1];
        const float4* e0 = (const float4*)&tab[QT9 + (t * 33 + k0) * 20];
        const float4* e1 = (const float4*)&tab[QT9 + (t * 33 + k1) * 20];
        u00 = f4add(u00, e0[0]); u01 = f4add(u01, e0[1]); u02 = f4add(u02, e0[2]); u03 = f4add(u03, e0[3]);
        u10 = f4add(u10, e1[0]); u11 = f4add(u11, e1[1]); u12 = f4add(u12, e1[2]); u13 = f4add(u13, e1[3]);
    }
    u00 = f4relu(u00); u01 = f4relu(u01); u02 = f4relu(u02); u03 = f4relu(u03);
    u10 = f4relu(u10); u11 = f4relu(u11); u12 = f4relu(u12); u13 = f4relu(u13);
    // ---- up2 (b2 baked into A2) ----
    float4 v00 = f4z(), v01 = f4z(), v02 = f4z(), v03 = f4z();
    float4 v10 = f4z(), v11 = f4z(), v12 = f4z(), v13 = f4z();
#define QUPD(I, S0, S1) { const float4* w4 = (const float4*)&tab[QU2 + (I) * 20]; \
    v00 = f4ma(v00, w4[0], S0); v01 = f4ma(v01, w4[1], S0); v02 = f4ma(v02, w4[2], S0); v03 = f4ma(v03, w4[3], S0); \
    v10 = f4ma(v10, w4[0], S1); v11 = f4ma(v11, w4[1], S1); v12 = f4ma(v12, w4[2], S1); v13 = f4ma(v13, w4[3], S1); }
    QUPD(0, u00.x, u10.x) QUPD(1, u00.y, u10.y) QUPD(2, u00.z, u10.z) QUPD(3, u00.w, u10.w)
    QUPD(4, u01.x, u11.x) QUPD(5, u01.y, u11.y) QUPD(6, u01.z, u11.z) QUPD(7, u01.w, u11.w)
    QUPD(8, u02.x, u12.x) QUPD(9, u02.y, u12.y) QUPD(10, u02.z, u12.z) QUPD(11, u02.w, u12.w)
    QUPD(12, u03.x, u13.x) QUPD(13, u03.y, u13.y) QUPD(14, u03.z, u13.z) QUPD(15, u03.w, u13.w)
#undef QUPD
    // ---- blend via per-code tables: z = A2[kc] + Bc[kc]*v ----
    int kc0 = ct[(ty + 1) * 40 + cx + 1], kc1 = ct[(ty + 1) * 40 + cx + 2];
    {
        const float4* a = (const float4*)&tab[QA2 + kc0 * 20];
        const float4* bb = (const float4*)&tab[QBC + kc0 * 20];
        v00 = f4fmav(a[0], bb[0], v00); v01 = f4fmav(a[1], bb[1], v01);
        v02 = f4fmav(a[2], bb[2], v02); v03 = f4fmav(a[3], bb[3], v03);
    }
    {
        const float4* a = (const float4*)&tab[QA2 + kc1 * 20];
        const float4* bb = (const float4*)&tab[QBC + kc1 * 20];
        v10 = f4fmav(a[0], bb[0], v10); v11 = f4fmav(a[1], bb[1], v11);
        v12 = f4fmav(a[2], bb[2], v12); v13 = f4fmav(a[3], bb[3], v13);
    }
    // ---- VQ both pixels ----
    float zz0 = dot16(v00, v01, v02, v03, v00, v01, v02, v03);
    float zz1 = dot16(v10, v11, v12, v13, v10, v11, v12, v13);
    float best0 = 3.4e38f, best1 = 3.4e38f; int bk0 = 0, bk1 = 0;
    #pragma unroll 8
    for (int k = 0; k < 32; ++k) {
        const float4* q = (const float4*)&tab[QCB + k * 20];
        float4 q0 = q[0], q1 = q[1], q2 = q[2], q3 = q[3];
        float cn = tab[QCB + k * 20 + 16];
        float d0 = (zz0 + cn) - 2.0f * dot16(q0, q1, q2, q3, v00, v01, v02, v03);
        float d1 = (zz1 + cn) - 2.0f * dot16(q0, q1, q2, q3, v10, v11, v12, v13);
        if (d0 < best0) { best0 = d0; bk0 = k; }
        if (d1 < best1) { best1 = d1; bk1 = k; }
    }
    unsigned short pr = (unsigned short)(bk0 | (bk1 << 8));
    *(unsigned short*)(idx_out + (size_t)b * (H_ * W_) + (size_t)(oy + ty) * W_ + ox + cx) = pr;
    const float4* qa = (const float4*)&tab[QCB + bk0 * 20];
    const float4* qbp = (const float4*)&tab[QCB + bk1 * 20];
    float lp = sq16(qa[0], qa[1], qa[2], qa[3], v00, v01, v02, v03)
             + sq16(qbp[0], qbp[1], qbp[2], qbp[3], v10, v11, v12, v13);
    for (int off = 32; off > 0; off >>= 1) lp += __shfl_down(lp, off, 64);
    if ((lid & 63) == 0) atomicAdd(lossS, (double)lp);
    atomicOr(&bm, (1u << bk0) | (1u << bk1));
    __syncthreads();
    if (lid == 0) atomicOr(maskS, bm);
}

// ---------------- final: decode LUT + scalar outputs ----------------
__global__ __launch_bounds__(256) void k_final(
    const unsigned char* __restrict__ idxF, const float* __restrict__ dlut,
    float* __restrict__ out, const double* __restrict__ lossS,
    const unsigned int* __restrict__ maskS)
{
    __shared__ float lut[32];
    if (threadIdx.x < 32) lut[threadIdx.x] = dlut[threadIdx.x];
    __syncthreads();
    size_t i = (size_t)blockIdx.x * 256 + threadIdx.x;
    uchar4 c4 = ((const uchar4*)idxF)[i];
    float4 o4 = make_float4(lut[c4.x], lut[c4.y], lut[c4.z], lut[c4.w]);
    ((float4*)out)[i] = o4;
    if (blockIdx.x == 0 && threadIdx.x == 0) {
        double vq = 0.0; float us = 0.f;
        for (int s = 0; s < 5; ++s) {
            vq += 1.25 * lossS[s] / 33554432.0;
            us += (float)__popc(maskS[s]) / 32.0f;
        }
        out[NPIX] = (float)(vq / 5.0);
        out[NPIX + 1] = us / 5.0f;
    }
}

extern "C" void kernel_launch(void* const* d_in, const int* in_sizes, int n_in,
                              void* d_out, int out_size, void* d_ws, size_t ws_size,
                              hipStream_t stream)
{
    const float* x   = (const float*)d_in[0];
    const float* stw = (const float*)d_in[1];
    const float* stb = (const float*)d_in[2];
    const float* w1  = (const float*)d_in[3];
    const float* b1  = (const float*)d_in[4];
    const float* u2w = (const float*)d_in[5];
    const float* b2  = (const float*)d_in[6];
    const float* tw  = (const float*)d_in[7];
    const float* tb  = (const float*)d_in[8];
    const float* cb  = (const float*)d_in[9];
    const float* dw  = (const float*)d_in[10];
    const float* db  = (const float*)d_in[11];

    char* ws = (char*)d_ws;
    unsigned char* idxA = (unsigned char*)ws;
    unsigned char* idxB = (unsigned char*)(ws + NPIX);
    float* gQ   = (float*)(ws + OFF_QTAB);
    float* gI   = (float*)(ws + OFF_ITAB);
    float* dlut = (float*)(ws + OFF_DLUT);
    double* lossS = (double*)(ws + OFF_LOSS);
    unsigned int* maskS = (unsigned int*)(ws + OFF_MASK);

    dim3 blk(16, 16, 1);
    dim3 g1(W_ / 16, H_ / 16, B_);      // iter1: 16x16 tiles
    dim3 gq(W_ / 32, H_ / 16, B_);      // qstep: 32x16 tiles (2 px/thread)
    k_setup<<<1, 256, 0, stream>>>(w1, b1, u2w, b2, tw, tb, cb, stw, stb, dw, db,
                                   gQ, gI, dlut, lossS, maskS);
    k_iter1<<<g1, blk, 0, stream>>>(x, gI, idxA, lossS + 0, maskS + 0);
    k_qstep<<<gq, blk, 0, stream>>>(idxA, idxB, gQ, lossS + 1, maskS + 1);
    k_qstep<<<gq, blk, 0, stream>>>(idxB, idxA, gQ, lossS + 2, maskS + 2);
    k_qstep<<<gq, blk, 0, stream>>>(idxA, idxB, gQ, lossS + 3, maskS + 3);
    k_qstep<<<gq, blk, 0, stream>>>(idxB, idxA, gQ, lossS + 4, maskS + 4);
    k_final<<<dim3((unsigned)(NPIX / 4 / 256)), 256, 0, stream>>>(idxA, dlut, (float*)d_out, lossS, maskS);
}

// Round 3
// 1042.336 us; speedup vs baseline: 2.4008x; 1.6042x over previous
//
#include <hip/hip_runtime.h>
#include <math.h>

#define DEV __device__ __forceinline__

namespace {
constexpr int B_ = 32, H_ = 256, W_ = 256;
constexpr size_t NPIX = (size_t)B_ * H_ * W_;   // 2,097,152

// ---- qstep table block (float offsets), entries stride 20 (80B, b128-aligned) ----
constexpr int QT9 = 0;            // [9][33] entries: T9[t][code][o] (+b1 baked into t==4)
constexpr int QCB = 5940;         // 32 entries: cb[c], slot16 = |cb|^2
constexpr int QA2 = 6580;         // 32 entries: beta*cb + (1-beta)*b2
constexpr int QBC = 7220;         // 32 entries: 1-beta
constexpr int QU2 = 7860;         // 16 entries: up2w transposed [i][o]
constexpr int QTOT = 8180;        // floats (32,720 B), /4 = 2045 exact

// ---- iter1 table block (broadcast-only tables unpadded: stride 16) ----
constexpr int IW1 = 0;            // [9*16] entries stride16: w1[t][i][o]
constexpr int IU2 = 2304;         // 16 entries stride16: up2w^T [i][o]
constexpr int ITA = 2560;         // 16 entries stride16: tauw^T [i][c]
constexpr int ICB = 2816;         // 32 entries stride20: cb + |cb|^2 at +16
constexpr int IB1 = 3456;         // 16 floats
constexpr int IB2 = 3472;         // 16
constexpr int ITB = 3488;         // 16 (tau bias)
constexpr int ISW = 3504;         // stem weights [9] entries stride16: sw[t][o]
constexpr int ISB = 3648;         // stem bias 16
constexpr int ITOT = 3664;        // floats (14,656 B), /4 = 916 exact

// ws byte offsets
constexpr size_t OFF_QTAB = 2 * NPIX;
constexpr size_t OFF_ITAB = OFF_QTAB + (size_t)QTOT * 4;
constexpr size_t OFF_DLUT = OFF_ITAB + (size_t)ITOT * 4;
constexpr size_t OFF_LOSS = (OFF_DLUT + 128 + 7) & ~(size_t)7;
constexpr size_t OFF_MASK = OFF_LOSS + 5 * 8;
}

DEV float4 f4z() { return make_float4(0.f, 0.f, 0.f, 0.f); }
DEV float4 f4ma(float4 a, float4 w, float s) {
    a.x = fmaf(w.x, s, a.x); a.y = fmaf(w.y, s, a.y);
    a.z = fmaf(w.z, s, a.z); a.w = fmaf(w.w, s, a.w); return a;
}
DEV float4 f4add(float4 a, float4 b) { a.x += b.x; a.y += b.y; a.z += b.z; a.w += b.w; return a; }
DEV float4 f4relu(float4 a) {
    a.x = fmaxf(a.x, 0.f); a.y = fmaxf(a.y, 0.f);
    a.z = fmaxf(a.z, 0.f); a.w = fmaxf(a.w, 0.f); return a;
}
DEV float4 f4fmav(float4 a, float4 b, float4 c) {   // a + b*c componentwise
    a.x = fmaf(b.x, c.x, a.x); a.y = fmaf(b.y, c.y, a.y);
    a.z = fmaf(b.z, c.z, a.z); a.w = fmaf(b.w, c.w, a.w); return a;
}
DEV float4 f4sig(float4 t) {
    t.x = 1.f / (1.f + expf(-t.x)); t.y = 1.f / (1.f + expf(-t.y));
    t.z = 1.f / (1.f + expf(-t.z)); t.w = 1.f / (1.f + expf(-t.w)); return t;
}
DEV float fget(float4 v, int i) { return i == 0 ? v.x : i == 1 ? v.y : i == 2 ? v.z : v.w; }
DEV float dot16(float4 a0, float4 a1, float4 a2, float4 a3,
                float4 b0, float4 b1, float4 b2, float4 b3) {
    float d = 0.f;
    d = fmaf(a0.x, b0.x, d); d = fmaf(a0.y, b0.y, d); d = fmaf(a0.z, b0.z, d); d = fmaf(a0.w, b0.w, d);
    d = fmaf(a1.x, b1.x, d); d = fmaf(a1.y, b1.y, d); d = fmaf(a1.z, b1.z, d); d = fmaf(a1.w, b1.w, d);
    d = fmaf(a2.x, b2.x, d); d = fmaf(a2.y, b2.y, d); d = fmaf(a2.z, b2.z, d); d = fmaf(a2.w, b2.w, d);
    d = fmaf(a3.x, b3.x, d); d = fmaf(a3.y, b3.y, d); d = fmaf(a3.z, b3.z, d); d = fmaf(a3.w, b3.w, d);
    return d;
}

// ---------------- setup: build all tables in ws, zero accumulators ----------------
__global__ void k_setup(const float* __restrict__ w1, const float* __restrict__ b1,
                        const float* __restrict__ u2w, const float* __restrict__ b2,
                        const float* __restrict__ tw, const float* __restrict__ tb,
                        const float* __restrict__ cb, const float* __restrict__ stw,
                        const float* __restrict__ stb, const float* __restrict__ dw,
                        const float* __restrict__ db,
                        float* __restrict__ gQ, float* __restrict__ gI,
                        float* __restrict__ dlut, double* __restrict__ lossS,
                        unsigned int* __restrict__ maskS)
{
    int tid = threadIdx.x;
    if (tid < 5) { lossS[tid] = 0.0; maskS[tid] = 0u; }
    for (int e = tid; e < 297; e += 256) {          // T9 entries (stride 20)
        int t = e / 33, k = e % 33;
        float* dst = &gQ[QT9 + e * 20];
        for (int o = 0; o < 16; ++o) {
            float acc = 0.f;
            if (k < 32) {
                for (int i = 0; i < 16; ++i)
                    acc = fmaf(w1[o * 144 + i * 9 + t], cb[k * 16 + i], acc);
                if (t == 4) acc += b1[o];
            }
            dst[o] = acc;
        }
        dst[16] = dst[17] = dst[18] = dst[19] = 0.f;
    }
    if (tid < 32) {
        int k = tid;
        float nrm = 0.f;
        for (int c = 0; c < 16; ++c) { float v = cb[k * 16 + c]; nrm = fmaf(v, v, nrm); }
        for (int c = 0; c < 16; ++c) { gQ[QCB + k * 20 + c] = cb[k * 16 + c]; gI[ICB + k * 20 + c] = cb[k * 16 + c]; }
        gQ[QCB + k * 20 + 16] = nrm; gI[ICB + k * 20 + 16] = nrm;
        for (int c = 17; c < 20; ++c) { gQ[QCB + k * 20 + c] = 0.f; gI[ICB + k * 20 + c] = 0.f; }
        float dacc = db[0];
        for (int c = 0; c < 16; ++c) dacc = fmaf(dw[c], cb[k * 16 + c], dacc);
        dlut[k] = 1.f / (1.f + expf(-dacc));
        for (int c = 0; c < 16; ++c) {
            float ta = tb[c];
            for (int i = 0; i < 16; ++i) ta = fmaf(tw[c * 16 + i], cb[k * 16 + i], ta);
            float beta = 1.f / (1.f + expf(-ta));
            gQ[QA2 + k * 20 + c] = beta * cb[k * 16 + c] + (1.f - beta) * b2[c];
            gQ[QBC + k * 20 + c] = 1.f - beta;
        }
        for (int c = 16; c < 20; ++c) { gQ[QA2 + k * 20 + c] = 0.f; gQ[QBC + k * 20 + c] = 0.f; }
    }
    if (tid < 16) {
        int i = tid;
        for (int o = 0; o < 16; ++o) {
            gQ[QU2 + i * 20 + o] = u2w[o * 16 + i];
            gI[IU2 + i * 16 + o] = u2w[o * 16 + i];
            gI[ITA + i * 16 + o] = tw[o * 16 + i];   // tau^T: [i][c]
        }
        for (int o = 16; o < 20; ++o) gQ[QU2 + i * 20 + o] = 0.f;
        gI[IB1 + i] = b1[i]; gI[IB2 + i] = b2[i]; gI[ITB + i] = tb[i]; gI[ISB + i] = stb[i];
    }
    for (int e = tid; e < 144; e += 256) {          // w1 rearranged [t][i][o], stride 16
        int t = e / 16, i = e % 16;
        float* dst = &gI[IW1 + e * 16];
        for (int o = 0; o < 16; ++o) dst[o] = w1[o * 144 + i * 9 + t];
    }
    if (tid < 9) {
        int t = tid;
        for (int o = 0; o < 16; ++o) gI[ISW + t * 16 + o] = stw[o * 9 + t];
    }
}

// ---------------- step 1: fused stem + up1/up2/tau/blend + VQ, 2 px/thread ----------------
__global__ __launch_bounds__(256, 2) void k_iter1(
    const float* __restrict__ x, const float* __restrict__ gI,
    unsigned char* __restrict__ idx_out, double* __restrict__ lossS,
    unsigned int* __restrict__ maskS)
{
    __shared__ float xt[20 * 36];       // input tile (tile 32x16 -> 36x20 halo)
    __shared__ float st[612 * 20];      // state0 AoS [18 rows x 34 cols][20]
    __shared__ float tab[ITOT];
    __shared__ double dsum[4];
    __shared__ unsigned int msum[4];
    const int lx = threadIdx.x, ly = threadIdx.y;
    const int lid = ly * 16 + lx;
    const int b = blockIdx.z, oy = blockIdx.y * 16, ox = blockIdx.x * 32;
    for (int i = lid; i < ITOT / 4; i += 256) ((float4*)tab)[i] = ((const float4*)gI)[i];
    const float* xb = x + (size_t)b * (H_ * W_);
    for (int i = lid; i < 720; i += 256) {
        int iy = i / 36, ix = i % 36;
        int gy = oy - 2 + iy, gx = ox - 2 + ix;
        float v = 0.f;
        if ((unsigned)gy < (unsigned)H_ && (unsigned)gx < (unsigned)W_) v = xb[gy * W_ + gx];
        xt[i] = v;
    }
    __syncthreads();
    for (int q = lid; q < 612; q += 256) {          // stem conv -> st (relu, zero outside)
        int sy = q / 34, sx = q % 34;
        int gy = oy - 1 + sy, gx = ox - 1 + sx;
        bool inb = ((unsigned)gy < (unsigned)H_ && (unsigned)gx < (unsigned)W_);
        float4 a0 = *(const float4*)&tab[ISB];
        float4 a1 = *(const float4*)&tab[ISB + 4];
        float4 a2 = *(const float4*)&tab[ISB + 8];
        float4 a3 = *(const float4*)&tab[ISB + 12];
        #pragma unroll
        for (int t = 0; t < 9; ++t) {
            float xv = xt[(sy + t / 3) * 36 + sx + t % 3];
            const float4* w4 = (const float4*)&tab[ISW + t * 16];
            a0 = f4ma(a0, w4[0], xv); a1 = f4ma(a1, w4[1], xv);
            a2 = f4ma(a2, w4[2], xv); a3 = f4ma(a3, w4[3], xv);
        }
        a0 = f4relu(a0); a1 = f4relu(a1); a2 = f4relu(a2); a3 = f4relu(a3);
        if (!inb) { a0 = f4z(); a1 = f4z(); a2 = f4z(); a3 = f4z(); }
        float4* d = (float4*)&st[q * 20];
        d[0] = a0; d[1] = a1; d[2] = a2; d[3] = a3;
    }
    __syncthreads();
    const int cx = lx * 2;
    // ---- up1: 9 taps; each weight b128 feeds 2 pixels ----
    float4 u00 = ((const float4*)&tab[IB1])[0], u01 = ((const float4*)&tab[IB1])[1],
           u02 = ((const float4*)&tab[IB1])[2], u03 = ((const float4*)&tab[IB1])[3];
    float4 u10 = u00, u11 = u01, u12 = u02, u13 = u03;
#define UPD1(E, S0, S1) { const float4* w4 = (const float4*)&tab[IW1 + (E) * 16]; \
    float4 wa = w4[0], wb = w4[1], wc = w4[2], wd = w4[3]; \
    u00 = f4ma(u00, wa, S0); u01 = f4ma(u01, wb, S0); u02 = f4ma(u02, wc, S0); u03 = f4ma(u03, wd, S0); \
    u10 = f4ma(u10, wa, S1); u11 = f4ma(u11, wb, S1); u12 = f4ma(u12, wc, S1); u13 = f4ma(u13, wd, S1); }
    #pragma unroll
    for (int t = 0; t < 9; ++t) {
        const float4* sp0 = (const float4*)&st[((ly + t / 3) * 34 + cx + t % 3) * 20];
        const float4* sp1 = sp0 + 5;    // next column (stride 20 floats)
        float4 sA0 = sp0[0], sB0 = sp0[1], sC0 = sp0[2], sD0 = sp0[3];
        float4 sA1 = sp1[0], sB1 = sp1[1], sC1 = sp1[2], sD1 = sp1[3];
        const int e = t * 16;
        UPD1(e + 0, sA0.x, sA1.x) UPD1(e + 1, sA0.y, sA1.y) UPD1(e + 2, sA0.z, sA1.z) UPD1(e + 3, sA0.w, sA1.w)
        UPD1(e + 4, sB0.x, sB1.x) UPD1(e + 5, sB0.y, sB1.y) UPD1(e + 6, sB0.z, sB1.z) UPD1(e + 7, sB0.w, sB1.w)
        UPD1(e + 8, sC0.x, sC1.x) UPD1(e + 9, sC0.y, sC1.y) UPD1(e + 10, sC0.z, sC1.z) UPD1(e + 11, sC0.w, sC1.w)
        UPD1(e + 12, sD0.x, sD1.x) UPD1(e + 13, sD0.y, sD1.y) UPD1(e + 14, sD0.z, sD1.z) UPD1(e + 15, sD0.w, sD1.w)
    }
#undef UPD1
    u00 = f4relu(u00); u01 = f4relu(u01); u02 = f4relu(u02); u03 = f4relu(u03);
    u10 = f4relu(u10); u11 = f4relu(u11); u12 = f4relu(u12); u13 = f4relu(u13);
    const float4* cp0 = (const float4*)&st[((ly + 1) * 34 + cx + 1) * 20];
    const float4* cp1 = cp0 + 5;
    float4 c00 = cp0[0], c01 = cp0[1], c02 = cp0[2], c03 = cp0[3];
    float4 c10 = cp1[0], c11 = cp1[1], c12 = cp1[2], c13 = cp1[3];
    // ---- up2 (both px share weight loads) ----
    float4 v00 = ((const float4*)&tab[IB2])[0], v01 = ((const float4*)&tab[IB2])[1],
           v02 = ((const float4*)&tab[IB2])[2], v03 = ((const float4*)&tab[IB2])[3];
    float4 v10 = v00, v11 = v01, v12 = v02, v13 = v03;
#define UPD2(I, S0, S1) { const float4* w4 = (const float4*)&tab[IU2 + (I) * 16]; \
    float4 wa = w4[0], wb = w4[1], wc = w4[2], wd = w4[3]; \
    v00 = f4ma(v00, wa, S0); v01 = f4ma(v01, wb, S0); v02 = f4ma(v02, wc, S0); v03 = f4ma(v03, wd, S0); \
    v10 = f4ma(v10, wa, S1); v11 = f4ma(v11, wb, S1); v12 = f4ma(v12, wc, S1); v13 = f4ma(v13, wd, S1); }
    UPD2(0, u00.x, u10.x) UPD2(1, u00.y, u10.y) UPD2(2, u00.z, u10.z) UPD2(3, u00.w, u10.w)
    UPD2(4, u01.x, u11.x) UPD2(5, u01.y, u11.y) UPD2(6, u01.z, u11.z) UPD2(7, u01.w, u11.w)
    UPD2(8, u02.x, u12.x) UPD2(9, u02.y, u12.y) UPD2(10, u02.z, u12.z) UPD2(11, u02.w, u12.w)
    UPD2(12, u03.x, u13.x) UPD2(13, u03.y, u13.y) UPD2(14, u03.z, u13.z) UPD2(15, u03.w, u13.w)
#undef UPD2
    // ---- tau (shares center values) ----
    float4 t00 = ((const float4*)&tab[ITB])[0], t01 = ((const float4*)&tab[ITB])[1],
           t02 = ((const float4*)&tab[ITB])[2], t03 = ((const float4*)&tab[ITB])[3];
    float4 t10 = t00, t11 = t01, t12 = t02, t13 = t03;
#define UPDT(I, S0, S1) { const float4* w4 = (const float4*)&tab[ITA + (I) * 16]; \
    float4 wa = w4[0], wb = w4[1], wc = w4[2], wd = w4[3]; \
    t00 = f4ma(t00, wa, S0); t01 = f4ma(t01, wb, S0); t02 = f4ma(t02, wc, S0); t03 = f4ma(t03, wd, S0); \
    t10 = f4ma(t10, wa, S1); t11 = f4ma(t11, wb, S1); t12 = f4ma(t12, wc, S1); t13 = f4ma(t13, wd, S1); }
    UPDT(0, c00.x, c10.x) UPDT(1, c00.y, c10.y) UPDT(2, c00.z, c10.z) UPDT(3, c00.w, c10.w)
    UPDT(4, c01.x, c11.x) UPDT(5, c01.y, c11.y) UPDT(6, c01.z, c11.z) UPDT(7, c01.w, c11.w)
    UPDT(8, c02.x, c12.x) UPDT(9, c02.y, c12.y) UPDT(10, c02.z, c12.z) UPDT(11, c02.w, c12.w)
    UPDT(12, c03.x, c13.x) UPDT(13, c03.y, c13.y) UPDT(14, c03.z, c13.z) UPDT(15, c03.w, c13.w)
#undef UPDT
    // blend: z = v + sig(t)*(c - v)
    float4 z00, z01, z02, z03, z10, z11, z12, z13;
#define BLEND(Z, T, C, V) { float4 e = f4sig(T); \
    Z.x = fmaf(e.x, C.x - V.x, V.x); Z.y = fmaf(e.y, C.y - V.y, V.y); \
    Z.z = fmaf(e.z, C.z - V.z, V.z); Z.w = fmaf(e.w, C.w - V.w, V.w); }
    BLEND(z00, t00, c00, v00) BLEND(z01, t01, c01, v01) BLEND(z02, t02, c02, v02) BLEND(z03, t03, c03, v03)
    BLEND(z10, t10, c10, v10) BLEND(z11, t11, c11, v11) BLEND(z12, t12, c12, v12) BLEND(z13, t13, c13, v13)
#undef BLEND
    // ---- VQ (cb reads feed both px) ----
    float zz0 = dot16(z00, z01, z02, z03, z00, z01, z02, z03);
    float zz1 = dot16(z10, z11, z12, z13, z10, z11, z12, z13);
    float best0 = 3.4e38f, best1 = 3.4e38f; int bk0 = 0, bk1 = 0;
    #pragma unroll 8
    for (int k = 0; k < 32; ++k) {
        const float4* q = (const float4*)&tab[ICB + k * 20];
        float4 q0 = q[0], q1 = q[1], q2 = q[2], q3 = q[3];
        float cn = tab[ICB + k * 20 + 16];
        float d0 = (zz0 + cn) - 2.0f * dot16(q0, q1, q2, q3, z00, z01, z02, z03);
        float d1 = (zz1 + cn) - 2.0f * dot16(q0, q1, q2, q3, z10, z11, z12, z13);
        if (d0 < best0) { best0 = d0; bk0 = k; }
        if (d1 < best1) { best1 = d1; bk1 = k; }
    }
    unsigned short pr = (unsigned short)(bk0 | (bk1 << 8));
    *(unsigned short*)(idx_out + (size_t)b * (H_ * W_) + (size_t)(oy + ly) * W_ + ox + cx) = pr;
    float lp = best0 + best1;                       // == ||z-cb_bk||^2 sums (d-form)
    unsigned int m = (1u << bk0) | (1u << bk1);
    #pragma unroll
    for (int off = 32; off > 0; off >>= 1) {
        lp += __shfl_down(lp, off, 64);
        m |= __shfl_down(m, off, 64);
    }
    if ((lid & 63) == 0) { dsum[lid >> 6] = (double)lp; msum[lid >> 6] = m; }
    __syncthreads();
    if (lid == 0) {
        atomicAdd(lossS, dsum[0] + dsum[1] + dsum[2] + dsum[3]);
        atomicOr(maskS, msum[0] | msum[1] | msum[2] | msum[3]);
    }
}

// ---------------- steps 2..5: table-driven, 4 px/thread ----------------
__global__ __launch_bounds__(256, 3) void k_qstep(
    const unsigned char* __restrict__ idx_in, unsigned char* __restrict__ idx_out,
    const float* __restrict__ gQ, double* __restrict__ lossS,
    unsigned int* __restrict__ maskS)
{
    __shared__ float tab[QTOT];             // 32,720 B
    __shared__ unsigned char ct[18 * 80];   // 18 rows x 66 cols used (stride 80)
    __shared__ double dsum[4];
    __shared__ unsigned int msum[4];
    const int tx = threadIdx.x, ty = threadIdx.y;
    const int lid = ty * 16 + tx;
    const int b = blockIdx.z, oy = blockIdx.y * 16, ox = blockIdx.x * 64;
    for (int i = lid; i < QTOT / 4; i += 256) ((float4*)tab)[i] = ((const float4*)gQ)[i];
    const unsigned char* ib = idx_in + (size_t)b * (H_ * W_);
    for (int i = lid; i < 18 * 66; i += 256) {
        int r = i / 66, c = i % 66;
        int gy = oy - 1 + r, gx = ox - 1 + c;
        unsigned char v = 32;               // sentinel -> zero vector
        if ((unsigned)gy < (unsigned)H_ && (unsigned)gx < (unsigned)W_) v = ib[gy * W_ + gx];
        ct[r * 80 + c] = v;
    }
    __syncthreads();
    const int cx = tx * 4;
    // load this thread's 3x6 code patch (2 packed u32 per row)
    int K[3][6];
    #pragma unroll
    for (int r = 0; r < 3; ++r) {
        unsigned int w0 = *(const unsigned int*)&ct[(ty + r) * 80 + cx];
        unsigned int w1 = *(const unsigned int*)&ct[(ty + r) * 80 + cx + 4];
        K[r][0] = w0 & 255; K[r][1] = (w0 >> 8) & 255; K[r][2] = (w0 >> 16) & 255;
        K[r][3] = w0 >> 24; K[r][4] = w1 & 255; K[r][5] = (w1 >> 8) & 255;
    }
    float4 U[4][4];
    #pragma unroll
    for (int p = 0; p < 4; ++p)
        #pragma unroll
        for (int c = 0; c < 4; ++c) U[p][c] = f4z();
    #pragma unroll
    for (int t = 0; t < 9; ++t) {           // up1 conv = 9 table gathers x 4 px
        const int dy = t / 3, dx = t % 3;
        #pragma unroll
        for (int p = 0; p < 4; ++p) {
            const float4* e = (const float4*)&tab[QT9 + (t * 33 + K[dy][p + dx]) * 20];
            U[p][0] = f4add(U[p][0], e[0]); U[p][1] = f4add(U[p][1], e[1]);
            U[p][2] = f4add(U[p][2], e[2]); U[p][3] = f4add(U[p][3], e[3]);
        }
    }
    #pragma unroll
    for (int p = 0; p < 4; ++p)
        #pragma unroll
        for (int c = 0; c < 4; ++c) U[p][c] = f4relu(U[p][c]);
    // ---- up2: each weight b128 feeds 4 px ----
    float4 V[4][4];
    #pragma unroll
    for (int p = 0; p < 4; ++p)
        #pragma unroll
        for (int c = 0; c < 4; ++c) V[p][c] = f4z();
    #pragma unroll
    for (int i = 0; i < 16; ++i) {
        const float4* w4 = (const float4*)&tab[QU2 + i * 20];
        float4 wa = w4[0], wb = w4[1], wc = w4[2], wd = w4[3];
        #pragma unroll
        for (int p = 0; p < 4; ++p) {
            float s = fget(U[p][i >> 2], i & 3);
            V[p][0] = f4ma(V[p][0], wa, s); V[p][1] = f4ma(V[p][1], wb, s);
            V[p][2] = f4ma(V[p][2], wc, s); V[p][3] = f4ma(V[p][3], wd, s);
        }
    }
    // ---- blend via per-code tables: z = A2[kc] + Bc[kc]*v ----
    #pragma unroll
    for (int p = 0; p < 4; ++p) {
        int kc = K[1][p + 1];
        const float4* a = (const float4*)&tab[QA2 + kc * 20];
        const float4* bb = (const float4*)&tab[QBC + kc * 20];
        V[p][0] = f4fmav(a[0], bb[0], V[p][0]); V[p][1] = f4fmav(a[1], bb[1], V[p][1]);
        V[p][2] = f4fmav(a[2], bb[2], V[p][2]); V[p][3] = f4fmav(a[3], bb[3], V[p][3]);
    }
    // ---- VQ all 4 px (cb reads amortized 4x) ----
    float zz[4], best[4]; int bk[4];
    #pragma unroll
    for (int p = 0; p < 4; ++p) {
        zz[p] = dot16(V[p][0], V[p][1], V[p][2], V[p][3], V[p][0], V[p][1], V[p][2], V[p][3]);
        best[p] = 3.4e38f; bk[p] = 0;
    }
    #pragma unroll 8
    for (int k = 0; k < 32; ++k) {
        const float4* q = (const float4*)&tab[QCB + k * 20];
        float4 q0 = q[0], q1 = q[1], q2 = q[2], q3 = q[3];
        float cn = tab[QCB + k * 20 + 16];
        #pragma unroll
        for (int p = 0; p < 4; ++p) {
            float d = (zz[p] + cn) - 2.0f * dot16(q0, q1, q2, q3, V[p][0], V[p][1], V[p][2], V[p][3]);
            if (d < best[p]) { best[p] = d; bk[p] = k; }
        }
    }
    unsigned int pack = (unsigned)bk[0] | ((unsigned)bk[1] << 8) | ((unsigned)bk[2] << 16) | ((unsigned)bk[3] << 24);
    *(unsigned int*)(idx_out + (size_t)b * (H_ * W_) + (size_t)(oy + ty) * W_ + ox + cx) = pack;
    float lp = best[0] + best[1] + best[2] + best[3];
    unsigned int m = (1u << bk[0]) | (1u << bk[1]) | (1u << bk[2]) | (1u << bk[3]);
    #pragma unroll
    for (int off = 32; off > 0; off >>= 1) {
        lp += __shfl_down(lp, off, 64);
        m |= __shfl_down(m, off, 64);
    }
    if ((lid & 63) == 0) { dsum[lid >> 6] = (double)lp; msum[lid >> 6] = m; }
    __syncthreads();
    if (lid == 0) {
        atomicAdd(lossS, dsum[0] + dsum[1] + dsum[2] + dsum[3]);
        atomicOr(maskS, msum[0] | msum[1] | msum[2] | msum[3]);
    }
}

// ---------------- final: decode LUT + scalar outputs ----------------
__global__ __launch_bounds__(256) void k_final(
    const unsigned char* __restrict__ idxF, const float* __restrict__ dlut,
    float* __restrict__ out, const double* __restrict__ lossS,
    const unsigned int* __restrict__ maskS)
{
    __shared__ float lut[32];
    if (threadIdx.x < 32) lut[threadIdx.x] = dlut[threadIdx.x];
    __syncthreads();
    size_t i = (size_t)blockIdx.x * 256 + threadIdx.x;
    uchar4 c4 = ((const uchar4*)idxF)[i];
    float4 o4 = make_float4(lut[c4.x], lut[c4.y], lut[c4.z], lut[c4.w]);
    ((float4*)out)[i] = o4;
    if (blockIdx.x == 0 && threadIdx.x == 0) {
        double vq = 0.0; float us = 0.f;
        for (int s = 0; s < 5; ++s) {
            vq += 1.25 * lossS[s] / 33554432.0;
            us += (float)__popc(maskS[s]) / 32.0f;
        }
        out[NPIX] = (float)(vq / 5.0);
        out[NPIX + 1] = us / 5.0f;
    }
}

extern "C" void kernel_launch(void* const* d_in, const int* in_sizes, int n_in,
                              void* d_out, int out_size, void* d_ws, size_t ws_size,
                              hipStream_t stream)
{
    const float* x   = (const float*)d_in[0];
    const float* stw = (const float*)d_in[1];
    const float* stb = (const float*)d_in[2];
    const float* w1  = (const float*)d_in[3];
    const float* b1  = (const float*)d_in[4];
    const float* u2w = (const float*)d_in[5];
    const float* b2  = (const float*)d_in[6];
    const float* tw  = (const float*)d_in[7];
    const float* tb  = (const float*)d_in[8];
    const float* cb  = (const float*)d_in[9];
    const float* dw  = (const float*)d_in[10];
    const float* db  = (const float*)d_in[11];

    char* ws = (char*)d_ws;
    unsigned char* idxA = (unsigned char*)ws;
    unsigned char* idxB = (unsigned char*)(ws + NPIX);
    float* gQ   = (float*)(ws + OFF_QTAB);
    float* gI   = (float*)(ws + OFF_ITAB);
    float* dlut = (float*)(ws + OFF_DLUT);
    double* lossS = (double*)(ws + OFF_LOSS);
    unsigned int* maskS = (unsigned int*)(ws + OFF_MASK);

    dim3 blk(16, 16, 1);
    dim3 g1(W_ / 32, H_ / 16, B_);      // iter1: 32x16 tiles, 2 px/thread
    dim3 gq(W_ / 64, H_ / 16, B_);      // qstep: 64x16 tiles, 4 px/thread
    k_setup<<<1, 256, 0, stream>>>(w1, b1, u2w, b2, tw, tb, cb, stw, stb, dw, db,
                                   gQ, gI, dlut, lossS, maskS);
    k_iter1<<<g1, blk, 0, stream>>>(x, gI, idxA, lossS + 0, maskS + 0);
    k_qstep<<<gq, blk, 0, stream>>>(idxA, idxB, gQ, lossS + 1, maskS + 1);
    k_qstep<<<gq, blk, 0, stream>>>(idxB, idxA, gQ, lossS + 2, maskS + 2);
    k_qstep<<<gq, blk, 0, stream>>>(idxA, idxB, gQ, lossS + 3, maskS + 3);
    k_qstep<<<gq, blk, 0, stream>>>(idxB, idxA, gQ, lossS + 4, maskS + 4);
    k_final<<<dim3((unsigned)(NPIX / 4 / 256)), 256, 0, stream>>>(idxA, dlut, (float*)d_out, lossS, maskS);
}

// Round 5
// 542.575 us; speedup vs baseline: 4.6122x; 1.9211x over previous
//
#include <hip/hip_runtime.h>
#include <math.h>

#define DEV __device__ __forceinline__

namespace {
constexpr int B_ = 32, H_ = 256, W_ = 256;
constexpr size_t NPIX = (size_t)B_ * H_ * W_;   // 2,097,152

// ---- qstep global table block (float offsets) ----
constexpr int QT9 = 0;            // [9][33] entries stride20: T9[t][code][o] (+b1 baked at t==4)
constexpr int QAB = 5940;         // A2: 32 entries stride20 (beta*cb+(1-beta)*b2); then Bc: 32 entries stride20
constexpr int QCB = 7220;         // 32 entries stride20: cb[c], slot16 = |cb|^2
constexpr int QU2 = 7860;         // 16 entries stride16: up2w^T [i][o]
constexpr int QTOT = 8116;
constexpr int QLDS = 7220;        // floats staged to LDS (T9 + A2/Bc)

// ---- iter1 global table block ----
constexpr int IW1 = 0;            // [9*16] entries stride16: w1[t][i][o]
constexpr int IU2 = 2304;         // 16 entries stride16: up2w^T [i][o]
constexpr int ITA = 2560;         // 16 entries stride16: tauw^T [i][c]
constexpr int ICB = 2816;         // 32 entries stride20: cb + |cb|^2 at +16
constexpr int IB1 = 3456;
constexpr int IB2 = 3472;
constexpr int ITB = 3488;
constexpr int ISB = 3504;
constexpr int ISW = 3520;         // 9 entries stride16
constexpr int ITOT = 3664;

// ws byte offsets
constexpr size_t OFF_QTAB = 2 * NPIX;
constexpr size_t OFF_ITAB = OFF_QTAB + (size_t)QTOT * 4;
constexpr size_t OFF_DLUT = OFF_ITAB + (size_t)ITOT * 4;
constexpr size_t OFF_LOSS = (OFF_DLUT + 128 + 7) & ~(size_t)7;
constexpr size_t OFF_MASK = OFF_LOSS + 5 * 8;
}

typedef float f2v __attribute__((ext_vector_type(2)));

struct V16 { f2v h[8]; };

DEV f2v fma2(f2v a, f2v b, f2v c) {       // a*b + c, elementwise (-> v_pk_fma_f32)
#if __has_builtin(__builtin_elementwise_fma)
    return __builtin_elementwise_fma(a, b, c);
#else
    f2v r; r.x = fmaf(a.x, b.x, c.x); r.y = fmaf(a.y, b.y, c.y); return r;
#endif
}
DEV f2v max2(f2v a, f2v b) {
#if __has_builtin(__builtin_elementwise_max)
    return __builtin_elementwise_max(a, b);
#else
    f2v r; r.x = fmaxf(a.x, b.x); r.y = fmaxf(a.y, b.y); return r;
#endif
}

DEV V16 v16z() {
    V16 r;
    #pragma unroll
    for (int j = 0; j < 8; ++j) r.h[j] = (f2v){0.f, 0.f};
    return r;
}
DEV void v16fma(V16& a, const V16& w, float s) {
    f2v ss = (f2v){s, s};
    #pragma unroll
    for (int j = 0; j < 8; ++j) a.h[j] = fma2(w.h[j], ss, a.h[j]);
}
DEV void v16add(V16& a, const V16& b) {
    #pragma unroll
    for (int j = 0; j < 8; ++j) a.h[j] = a.h[j] + b.h[j];
}
DEV void v16relu(V16& a) {
    f2v z = (f2v){0.f, 0.f};
    #pragma unroll
    for (int j = 0; j < 8; ++j) a.h[j] = max2(a.h[j], z);
}
DEV float v16dot(const V16& a, const V16& b) {
    f2v acc = (f2v){0.f, 0.f};
    #pragma unroll
    for (int j = 0; j < 8; ++j) acc = fma2(a.h[j], b.h[j], acc);
    return acc.x + acc.y;
}
DEV V16 ld16(const float* p) {            // 4x ds_read_b128 / s_load
    const float4* q = (const float4*)p;
    float4 A = q[0], Bv = q[1], C = q[2], D = q[3];
    V16 r;
    r.h[0] = (f2v){A.x, A.y};  r.h[1] = (f2v){A.z, A.w};
    r.h[2] = (f2v){Bv.x, Bv.y}; r.h[3] = (f2v){Bv.z, Bv.w};
    r.h[4] = (f2v){C.x, C.y};  r.h[5] = (f2v){C.z, C.w};
    r.h[6] = (f2v){D.x, D.y};  r.h[7] = (f2v){D.z, D.w};
    return r;
}
DEV void st16(float* p, const V16& v) {
    float4* q = (float4*)p;
    q[0] = make_float4(v.h[0].x, v.h[0].y, v.h[1].x, v.h[1].y);
    q[1] = make_float4(v.h[2].x, v.h[2].y, v.h[3].x, v.h[3].y);
    q[2] = make_float4(v.h[4].x, v.h[4].y, v.h[5].x, v.h[5].y);
    q[3] = make_float4(v.h[6].x, v.h[6].y, v.h[7].x, v.h[7].y);
}
DEV void v16sig(V16& a) {
    #pragma unroll
    for (int j = 0; j < 8; ++j) {
        a.h[j].x = 1.f / (1.f + expf(-a.h[j].x));
        a.h[j].y = 1.f / (1.f + expf(-a.h[j].y));
    }
}

// ---------------- setup ----------------
__global__ void k_setup(const float* __restrict__ w1, const float* __restrict__ b1,
                        const float* __restrict__ u2w, const float* __restrict__ b2,
                        const float* __restrict__ tw, const float* __restrict__ tb,
                        const float* __restrict__ cb, const float* __restrict__ stw,
                        const float* __restrict__ stb, const float* __restrict__ dw,
                        const float* __restrict__ db,
                        float* __restrict__ gQ, float* __restrict__ gI,
                        float* __restrict__ dlut, double* __restrict__ lossS,
                        unsigned int* __restrict__ maskS)
{
    int tid = threadIdx.x;
    if (tid < 5) { lossS[tid] = 0.0; maskS[tid] = 0u; }
    for (int e = tid; e < 297; e += 256) {          // T9 entries (stride 20)
        int t = e / 33, k = e % 33;
        float* dst = &gQ[QT9 + e * 20];
        for (int o = 0; o < 16; ++o) {
            float acc = 0.f;
            if (k < 32) {
                for (int i = 0; i < 16; ++i)
                    acc = fmaf(w1[o * 144 + i * 9 + t], cb[k * 16 + i], acc);
                if (t == 4) acc += b1[o];
            }
            dst[o] = acc;
        }
        dst[16] = dst[17] = dst[18] = dst[19] = 0.f;
    }
    if (tid < 32) {
        int k = tid;
        float nrm = 0.f;
        for (int c = 0; c < 16; ++c) { float v = cb[k * 16 + c]; nrm = fmaf(v, v, nrm); }
        for (int c = 0; c < 16; ++c) { gQ[QCB + k * 20 + c] = cb[k * 16 + c]; gI[ICB + k * 20 + c] = cb[k * 16 + c]; }
        gQ[QCB + k * 20 + 16] = nrm; gI[ICB + k * 20 + 16] = nrm;
        for (int c = 17; c < 20; ++c) { gQ[QCB + k * 20 + c] = 0.f; gI[ICB + k * 20 + c] = 0.f; }
        float dacc = db[0];
        for (int c = 0; c < 16; ++c) dacc = fmaf(dw[c], cb[k * 16 + c], dacc);
        dlut[k] = 1.f / (1.f + expf(-dacc));
        for (int c = 0; c < 16; ++c) {
            float ta = tb[c];
            for (int i = 0; i < 16; ++i) ta = fmaf(tw[c * 16 + i], cb[k * 16 + i], ta);
            float beta = 1.f / (1.f + expf(-ta));
            gQ[QAB + k * 20 + c] = beta * cb[k * 16 + c] + (1.f - beta) * b2[c];
            gQ[QAB + (32 + k) * 20 + c] = 1.f - beta;
        }
        for (int c = 16; c < 20; ++c) { gQ[QAB + k * 20 + c] = 0.f; gQ[QAB + (32 + k) * 20 + c] = 0.f; }
    }
    if (tid < 16) {
        int i = tid;
        for (int o = 0; o < 16; ++o) {
            gQ[QU2 + i * 16 + o] = u2w[o * 16 + i];
            gI[IU2 + i * 16 + o] = u2w[o * 16 + i];
            gI[ITA + i * 16 + o] = tw[o * 16 + i];   // tau^T
        }
        gI[IB1 + i] = b1[i]; gI[IB2 + i] = b2[i]; gI[ITB + i] = tb[i]; gI[ISB + i] = stb[i];
    }
    for (int e = tid; e < 144; e += 256) {          // w1 rearranged [t][i][o], stride 16
        int t = e / 16, i = e % 16;
        float* dst = &gI[IW1 + e * 16];
        for (int o = 0; o < 16; ++o) dst[o] = w1[o * 144 + i * 9 + t];
    }
    if (tid < 9) {
        int t = tid;
        for (int o = 0; o < 16; ++o) gI[ISW + t * 16 + o] = stw[o * 9 + t];
    }
}

// ---------------- step 1: stem + up1/up2/tau/blend + VQ, 2 px/thread ----------------
// State tile parity-split (stE even cols, stO odd cols) -> 2-way (free) LDS banking.
// All wave-uniform weight reads come from global (SMEM path), NOT LDS.
__global__ __launch_bounds__(256, 3) void k_iter1(
    const float* __restrict__ x, const float* __restrict__ gI,
    unsigned char* __restrict__ idx_out, double* __restrict__ lossS,
    unsigned int* __restrict__ maskS)
{
    __shared__ __align__(16) float xt[20 * 36];
    __shared__ __align__(16) float stE[306 * 20];   // even cols: 17 per row x 18 rows
    __shared__ __align__(16) float stO[306 * 20];   // odd cols
    __shared__ double dsum[4];
    __shared__ unsigned int msum[4];
    const int lx = threadIdx.x, ly = threadIdx.y;
    const int lid = ly * 16 + lx;
    const int b = blockIdx.z, oy = blockIdx.y * 16, ox = blockIdx.x * 32;
    const float* xb = x + (size_t)b * (H_ * W_);
    for (int i = lid; i < 720; i += 256) {
        int iy = i / 36, ix = i % 36;
        int gy = oy - 2 + iy, gx = ox - 2 + ix;
        float v = 0.f;
        if ((unsigned)gy < (unsigned)H_ && (unsigned)gx < (unsigned)W_) v = xb[gy * W_ + gx];
        xt[i] = v;
    }
    __syncthreads();
    for (int q = lid; q < 612; q += 256) {          // stem conv -> st (relu, zero outside)
        int sy = q / 34, sx = q % 34;
        int gy = oy - 1 + sy, gx = ox - 1 + sx;
        bool inb = ((unsigned)gy < (unsigned)H_ && (unsigned)gx < (unsigned)W_);
        V16 a = ld16(&gI[ISB]);
        #pragma unroll
        for (int t = 0; t < 9; ++t) {
            float xv = xt[(sy + t / 3) * 36 + sx + t % 3];
            V16 w = ld16(&gI[ISW + t * 16]);
            v16fma(a, w, xv);
        }
        v16relu(a);
        if (!inb) a = v16z();
        float* dst = ((sx & 1) ? stO : stE) + (sy * 17 + (sx >> 1)) * 20;
        st16(dst, a);
    }
    __syncthreads();
    // ---- up1: 9 taps; weights from global (uniform), state from parity LDS ----
    V16 u0 = ld16(&gI[IB1]);
    V16 u1 = u0;
    #pragma unroll
    for (int t = 0; t < 9; ++t) {
        const int r = ly + t / 3, dx = t % 3;
        const float* p0; const float* p1;
        if (dx == 0)      { p0 = &stE[(r * 17 + lx) * 20];     p1 = &stO[(r * 17 + lx) * 20]; }
        else if (dx == 1) { p0 = &stO[(r * 17 + lx) * 20];     p1 = &stE[(r * 17 + lx + 1) * 20]; }
        else              { p0 = &stE[(r * 17 + lx + 1) * 20]; p1 = &stO[(r * 17 + lx + 1) * 20]; }
        V16 s0 = ld16(p0), s1 = ld16(p1);
        const int base = IW1 + t * 256;             // (t*16 entries)*16
        #pragma unroll
        for (int j = 0; j < 8; ++j) {
            f2v a0 = s0.h[j], a1 = s1.h[j];
            V16 wA = ld16(&gI[base + (2 * j) * 16]);
            v16fma(u0, wA, a0.x); v16fma(u1, wA, a1.x);
            V16 wB = ld16(&gI[base + (2 * j + 1) * 16]);
            v16fma(u0, wB, a0.y); v16fma(u1, wB, a1.y);
        }
    }
    v16relu(u0); v16relu(u1);
    V16 c0 = ld16(&stO[((ly + 1) * 17 + lx) * 20]);       // center col = 2lx+1 (odd)
    V16 c1 = ld16(&stE[((ly + 1) * 17 + lx + 1) * 20]);   // center col = 2lx+2 (even)
    // ---- up2 ----
    V16 v0 = ld16(&gI[IB2]);
    V16 v1 = v0;
    #pragma unroll
    for (int j = 0; j < 8; ++j) {
        f2v a0 = u0.h[j], a1 = u1.h[j];
        V16 wA = ld16(&gI[IU2 + (2 * j) * 16]);
        v16fma(v0, wA, a0.x); v16fma(v1, wA, a1.x);
        V16 wB = ld16(&gI[IU2 + (2 * j + 1) * 16]);
        v16fma(v0, wB, a0.y); v16fma(v1, wB, a1.y);
    }
    // ---- tau ----
    V16 t0 = ld16(&gI[ITB]);
    V16 t1 = t0;
    #pragma unroll
    for (int j = 0; j < 8; ++j) {
        f2v a0 = c0.h[j], a1 = c1.h[j];
        V16 wA = ld16(&gI[ITA + (2 * j) * 16]);
        v16fma(t0, wA, a0.x); v16fma(t1, wA, a1.x);
        V16 wB = ld16(&gI[ITA + (2 * j + 1) * 16]);
        v16fma(t0, wB, a0.y); v16fma(t1, wB, a1.y);
    }
    v16sig(t0); v16sig(t1);
    // blend: z = v + sig(t)*(c - v)
    V16 z0, z1;
    #pragma unroll
    for (int j = 0; j < 8; ++j) {
        z0.h[j] = fma2(t0.h[j], c0.h[j] - v0.h[j], v0.h[j]);
        z1.h[j] = fma2(t1.h[j], c1.h[j] - v1.h[j], v1.h[j]);
    }
    // ---- VQ (cb from global uniform) ----
    float zz0 = v16dot(z0, z0), zz1 = v16dot(z1, z1);
    float best0 = 3.4e38f, best1 = 3.4e38f; int bk0 = 0, bk1 = 0;
    #pragma unroll 4
    for (int k = 0; k < 32; ++k) {
        V16 q = ld16(&gI[ICB + k * 20]);
        float cn = gI[ICB + k * 20 + 16];
        float d0 = (zz0 + cn) - 2.0f * v16dot(q, z0);
        float d1 = (zz1 + cn) - 2.0f * v16dot(q, z1);
        if (d0 < best0) { best0 = d0; bk0 = k; }
        if (d1 < best1) { best1 = d1; bk1 = k; }
    }
    unsigned short pr = (unsigned short)(bk0 | (bk1 << 8));
    *(unsigned short*)(idx_out + (size_t)b * (H_ * W_) + (size_t)(oy + ly) * W_ + ox + 2 * lx) = pr;
    float lp = best0 + best1;
    unsigned int m = (1u << bk0) | (1u << bk1);
    #pragma unroll
    for (int off = 32; off > 0; off >>= 1) {
        lp += __shfl_down(lp, off, 64);
        m |= __shfl_down(m, off, 64);
    }
    if ((lid & 63) == 0) { dsum[lid >> 6] = (double)lp; msum[lid >> 6] = m; }
    __syncthreads();
    if (lid == 0) {
        atomicAdd(lossS, dsum[0] + dsum[1] + dsum[2] + dsum[3]);
        atomicOr(maskS, msum[0] | msum[1] | msum[2] | msum[3]);
    }
}

// ---------------- steps 2..5: table-driven, 4 px/thread ----------------
// LDS holds only divergent-gather tables (T9, A2/Bc) + codes; uniform reads from global.
__global__ __launch_bounds__(256, 3) void k_qstep(
    const unsigned char* __restrict__ idx_in, unsigned char* __restrict__ idx_out,
    const float* __restrict__ gQ, double* __restrict__ lossS,
    unsigned int* __restrict__ maskS)
{
    __shared__ __align__(16) float tab[QLDS];       // T9 (5940) + A2/Bc (1280) = 28,880 B
    __shared__ unsigned char ct[18 * 80];
    __shared__ double dsum[4];
    __shared__ unsigned int msum[4];
    const int tx = threadIdx.x, ty = threadIdx.y;
    const int lid = ty * 16 + tx;
    const int b = blockIdx.z, oy = blockIdx.y * 16, ox = blockIdx.x * 64;
    for (int i = lid; i < QLDS / 4; i += 256) ((float4*)tab)[i] = ((const float4*)gQ)[i];
    const unsigned char* ib = idx_in + (size_t)b * (H_ * W_);
    for (int i = lid; i < 18 * 66; i += 256) {
        int r = i / 66, c = i % 66;
        int gy = oy - 1 + r, gx = ox - 1 + c;
        unsigned char v = 32;               // sentinel -> zero vector
        if ((unsigned)gy < (unsigned)H_ && (unsigned)gx < (unsigned)W_) v = ib[gy * W_ + gx];
        ct[r * 80 + c] = v;
    }
    __syncthreads();
    const int cx = tx * 4;
    int K[3][6];
    #pragma unroll
    for (int r = 0; r < 3; ++r) {
        unsigned int w0 = *(const unsigned int*)&ct[(ty + r) * 80 + cx];
        unsigned int w1 = *(const unsigned int*)&ct[(ty + r) * 80 + cx + 4];
        K[r][0] = w0 & 255; K[r][1] = (w0 >> 8) & 255; K[r][2] = (w0 >> 16) & 255;
        K[r][3] = w0 >> 24; K[r][4] = w1 & 255; K[r][5] = (w1 >> 8) & 255;
    }
    V16 V[4];
    // process px pairs to cap register pressure
    #pragma unroll
    for (int half = 0; half < 2; ++half) {
        V16 U0 = v16z(), U1 = v16z();
        const int p0 = half * 2, p1 = half * 2 + 1;
        #pragma unroll
        for (int t = 0; t < 9; ++t) {       // up1 = 9 gather-adds per px
            const int dy = t / 3, dx = t % 3;
            V16 e0 = ld16(&tab[(t * 33 + K[dy][p0 + dx]) * 20]);
            v16add(U0, e0);
            V16 e1 = ld16(&tab[(t * 33 + K[dy][p1 + dx]) * 20]);
            v16add(U1, e1);
        }
        v16relu(U0); v16relu(U1);
        // up2 (uniform weights from global; b2 baked into A2)
        V16 v0 = v16z(), v1 = v16z();
        #pragma unroll
        for (int j = 0; j < 8; ++j) {
            f2v a0 = U0.h[j], a1 = U1.h[j];
            V16 wA = ld16(&gQ[QU2 + (2 * j) * 16]);
            v16fma(v0, wA, a0.x); v16fma(v1, wA, a1.x);
            V16 wB = ld16(&gQ[QU2 + (2 * j + 1) * 16]);
            v16fma(v0, wB, a0.y); v16fma(v1, wB, a1.y);
        }
        // blend via per-code tables (LDS gather): z = A2[kc] + Bc[kc]*v
        {
            int kc = K[1][p0 + 1];
            V16 a = ld16(&tab[QAB + kc * 20]);
            V16 bb = ld16(&tab[QAB + (32 + kc) * 20]);
            #pragma unroll
            for (int j = 0; j < 8; ++j) v0.h[j] = fma2(bb.h[j], v0.h[j], a.h[j]);
        }
        {
            int kc = K[1][p1 + 1];
            V16 a = ld16(&tab[QAB + kc * 20]);
            V16 bb = ld16(&tab[QAB + (32 + kc) * 20]);
            #pragma unroll
            for (int j = 0; j < 8; ++j) v1.h[j] = fma2(bb.h[j], v1.h[j], a.h[j]);
        }
        V[p0] = v0; V[p1] = v1;
    }
    // ---- VQ all 4 px (cb from global uniform) ----
    float zz[4], best[4]; int bk[4];
    #pragma unroll
    for (int p = 0; p < 4; ++p) { zz[p] = v16dot(V[p], V[p]); best[p] = 3.4e38f; bk[p] = 0; }
    #pragma unroll 4
    for (int k = 0; k < 32; ++k) {
        V16 q = ld16(&gQ[QCB + k * 20]);
        float cn = gQ[QCB + k * 20 + 16];
        #pragma unroll
        for (int p = 0; p < 4; ++p) {
            float d = (zz[p] + cn) - 2.0f * v16dot(q, V[p]);
            if (d < best[p]) { best[p] = d; bk[p] = k; }
        }
    }
    unsigned int pack = (unsigned)bk[0] | ((unsigned)bk[1] << 8) | ((unsigned)bk[2] << 16) | ((unsigned)bk[3] << 24);
    *(unsigned int*)(idx_out + (size_t)b * (H_ * W_) + (size_t)(oy + ty) * W_ + ox + cx) = pack;
    float lp = best[0] + best[1] + best[2] + best[3];
    unsigned int m = (1u << bk[0]) | (1u << bk[1]) | (1u << bk[2]) | (1u << bk[3]);
    #pragma unroll
    for (int off = 32; off > 0; off >>= 1) {
        lp += __shfl_down(lp, off, 64);
        m |= __shfl_down(m, off, 64);
    }
    if ((lid & 63) == 0) { dsum[lid >> 6] = (double)lp; msum[lid >> 6] = m; }
    __syncthreads();
    if (lid == 0) {
        atomicAdd(lossS, dsum[0] + dsum[1] + dsum[2] + dsum[3]);
        atomicOr(maskS, msum[0] | msum[1] | msum[2] | msum[3]);
    }
}

// ---------------- final: decode LUT + scalar outputs ----------------
__global__ __launch_bounds__(256) void k_final(
    const unsigned char* __restrict__ idxF, const float* __restrict__ dlut,
    float* __restrict__ out, const double* __restrict__ lossS,
    const unsigned int* __restrict__ maskS)
{
    __shared__ float lut[32];
    if (threadIdx.x < 32) lut[threadIdx.x] = dlut[threadIdx.x];
    __syncthreads();
    size_t i = (size_t)blockIdx.x * 256 + threadIdx.x;
    uchar4 c4 = ((const uchar4*)idxF)[i];
    float4 o4 = make_float4(lut[c4.x], lut[c4.y], lut[c4.z], lut[c4.w]);
    ((float4*)out)[i] = o4;
    if (blockIdx.x == 0 && threadIdx.x == 0) {
        double vq = 0.0; float us = 0.f;
        for (int s = 0; s < 5; ++s) {
            vq += 1.25 * lossS[s] / 33554432.0;
            us += (float)__popc(maskS[s]) / 32.0f;
        }
        out[NPIX] = (float)(vq / 5.0);
        out[NPIX + 1] = us / 5.0f;
    }
}

extern "C" void kernel_launch(void* const* d_in, const int* in_sizes, int n_in,
                              void* d_out, int out_size, void* d_ws, size_t ws_size,
                              hipStream_t stream)
{
    const float* x   = (const float*)d_in[0];
    const float* stw = (const float*)d_in[1];
    const float* stb = (const float*)d_in[2];
    const float* w1  = (const float*)d_in[3];
    const float* b1  = (const float*)d_in[4];
    const float* u2w = (const float*)d_in[5];
    const float* b2  = (const float*)d_in[6];
    const float* tw  = (const float*)d_in[7];
    const float* tb  = (const float*)d_in[8];
    const float* cb  = (const float*)d_in[9];
    const float* dw  = (const float*)d_in[10];
    const float* db  = (const float*)d_in[11];

    char* ws = (char*)d_ws;
    unsigned char* idxA = (unsigned char*)ws;
    unsigned char* idxB = (unsigned char*)(ws + NPIX);
    float* gQ   = (float*)(ws + OFF_QTAB);
    float* gI   = (float*)(ws + OFF_ITAB);
    float* dlut = (float*)(ws + OFF_DLUT);
    double* lossS = (double*)(ws + OFF_LOSS);
    unsigned int* maskS = (unsigned int*)(ws + OFF_MASK);

    dim3 blk(16, 16, 1);
    dim3 g1(W_ / 32, H_ / 16, B_);      // iter1: 32x16 tiles, 2 px/thread
    dim3 gq(W_ / 64, H_ / 16, B_);      // qstep: 64x16 tiles, 4 px/thread
    k_setup<<<1, 256, 0, stream>>>(w1, b1, u2w, b2, tw, tb, cb, stw, stb, dw, db,
                                   gQ, gI, dlut, lossS, maskS);
    k_iter1<<<g1, blk, 0, stream>>>(x, gI, idxA, lossS + 0, maskS + 0);
    k_qstep<<<gq, blk, 0, stream>>>(idxA, idxB, gQ, lossS + 1, maskS + 1);
    k_qstep<<<gq, blk, 0, stream>>>(idxB, idxA, gQ, lossS + 2, maskS + 2);
    k_qstep<<<gq, blk, 0, stream>>>(idxA, idxB, gQ, lossS + 3, maskS + 3);
    k_qstep<<<gq, blk, 0, stream>>>(idxB, idxA, gQ, lossS + 4, maskS + 4);
    k_final<<<dim3((unsigned)(NPIX / 4 / 256)), 256, 0, stream>>>(idxA, dlut, (float*)d_out, lossS, maskS);
}